// Round 7
// baseline (1866.284 us; speedup 1.0000x reference)
//
#include <hip/hip_runtime.h>
#include <hip/hip_bf16.h>

#define DEVFN __device__ __forceinline__

DEVFN float lrelu(float v) { return (v >= 0.f) ? v : 0.2f * v; }

DEVFN float wave_sum(float v) {
#pragma unroll
  for (int o = 1; o < 64; o <<= 1) v += __shfl_xor(v, o, 64);
  return v;
}
DEVFN float wave_max(float v) {
#pragma unroll
  for (int o = 1; o < 64; o <<= 1) v = fmaxf(v, __shfl_xor(v, o, 64));
  return v;
}

// ---------------------------------------------------------------------------
// Tiled GEMM H = X @ W.  K=128 fixed; C in {64,128}. ROWS=16 rows per block,
// 256 threads. W fully staged in LDS (K*C floats), X tile staged too.
// ---------------------------------------------------------------------------
template<int K, int C>
__global__ __launch_bounds__(256) void gemm_tiled(const float* __restrict__ X,
                                                  const float* __restrict__ W,
                                                  float* __restrict__ H, int N) {
  constexpr int ROWS = 16;
  constexpr int TM = ROWS / (256 / C);   // 8 for C=128, 4 for C=64
  __shared__ float Ws[K * C];
  __shared__ float Xs[ROWS * K];

  const int t = threadIdx.x;
  const int row0 = blockIdx.x * ROWS;
  const int nrow = min(ROWS, N - row0);

  const float4* Wv = (const float4*)W;
#pragma unroll 4
  for (int i = t; i < K * C / 4; i += 256) ((float4*)Ws)[i] = Wv[i];
  const float4* Xv = (const float4*)(X + (size_t)row0 * K);
  const int xcnt = nrow * K / 4;
  for (int i = t; i < xcnt; i += 256) ((float4*)Xs)[i] = Xv[i];
  __syncthreads();

  const int c = t % C;
  const int g = t / C;
  float acc[TM];
#pragma unroll
  for (int r = 0; r < TM; ++r) acc[r] = 0.f;

#pragma unroll 2
  for (int k = 0; k < K; k += 4) {
    float w0 = Ws[(k + 0) * C + c];
    float w1 = Ws[(k + 1) * C + c];
    float w2 = Ws[(k + 2) * C + c];
    float w3 = Ws[(k + 3) * C + c];
#pragma unroll
    for (int r = 0; r < TM; ++r) {
      float4 xv = *(const float4*)&Xs[(g * TM + r) * K + k];
      acc[r] += xv.x * w0 + xv.y * w1 + xv.z * w2 + xv.w * w3;
    }
  }
#pragma unroll
  for (int r = 0; r < TM; ++r) {
    int row = g * TM + r;
    if (row < nrow) H[(size_t)(row0 + row) * C + c] = acc[r];
  }
}

// ---------------------------------------------------------------------------
// Attention scores per node: es = h . a_src, ed = h . a_dst. One wave/node.
// ---------------------------------------------------------------------------
template<int C>
__global__ void escore(const float* __restrict__ H,
                       const float* __restrict__ a_src,
                       const float* __restrict__ a_dst,
                       float* __restrict__ es, float* __restrict__ ed, int N) {
  const int lane = threadIdx.x & 63;
  const int n = blockIdx.x * (blockDim.x >> 6) + (threadIdx.x >> 6);
  if (n >= N) return;
  float ps, pd;
  if (C == 128) {
    float2 h = ((const float2*)H)[(size_t)n * 64 + lane];
    float2 as_ = ((const float2*)a_src)[lane];
    float2 ad_ = ((const float2*)a_dst)[lane];
    ps = h.x * as_.x + h.y * as_.y;
    pd = h.x * ad_.x + h.y * ad_.y;
  } else {
    float h = H[(size_t)n * C + lane];
    ps = h * a_src[lane];
    pd = h * a_dst[lane];
  }
  ps = wave_sum(ps);
  pd = wave_sum(pd);
  if (lane == 0) { es[n] = ps; ed[n] = pd; }
}

// ---------------------------------------------------------------------------
// CSR build: fused deg+bucket histogram -> scans -> two-level scatter.
// bucket = dst >> 7  (128 dst nodes per bucket => ~4K edges, 16KB COL region)
// ---------------------------------------------------------------------------
__global__ void count_deg_bkt(const int* __restrict__ dst, int* __restrict__ deg,
                              int* __restrict__ bcnt, int E) {
  int e = blockIdx.x * blockDim.x + threadIdx.x;
  if (e < E) {
    int d = dst[e];
    atomicAdd(deg + d, 1);
    atomicAdd(bcnt + (d >> 7), 1);
  }
}

__global__ void scan_partial(const int* __restrict__ deg, int* __restrict__ csum, int N) {
  __shared__ int sh[256];
  int i = blockIdx.x * 256 + threadIdx.x;
  sh[threadIdx.x] = (i < N) ? deg[i] : 0;
  __syncthreads();
  for (int o = 128; o > 0; o >>= 1) {
    if (threadIdx.x < o) sh[threadIdx.x] += sh[threadIdx.x + o];
    __syncthreads();
  }
  if (threadIdx.x == 0) csum[blockIdx.x] = sh[0];
}

// Exclusive scan in place (single block, loop with carry). Used for chunk sums
// and for the bucket histogram (result doubles as write cursors).
__global__ void scan_chunks(int* __restrict__ csum, int nch) {
  __shared__ int sh[256];
  __shared__ int carry;
  if (threadIdx.x == 0) carry = 0;
  __syncthreads();
  for (int base = 0; base < nch; base += 256) {
    int i = base + threadIdx.x;
    int v = (i < nch) ? csum[i] : 0;
    sh[threadIdx.x] = v;
    __syncthreads();
    for (int o = 1; o < 256; o <<= 1) {
      int t = (threadIdx.x >= o) ? sh[threadIdx.x - o] : 0;
      __syncthreads();
      sh[threadIdx.x] += t;
      __syncthreads();
    }
    if (i < nch) csum[i] = carry + sh[threadIdx.x] - v;
    __syncthreads();
    if (threadIdx.x == 255) carry += sh[255];
    __syncthreads();
  }
}

__global__ void scan_final(const int* __restrict__ deg, const int* __restrict__ csum,
                           int* __restrict__ rp, int* __restrict__ wp, int N, int E) {
  __shared__ int sh[256];
  int i = blockIdx.x * 256 + threadIdx.x;
  int v = (i < N) ? deg[i] : 0;
  sh[threadIdx.x] = v;
  __syncthreads();
  for (int o = 1; o < 256; o <<= 1) {
    int t = (threadIdx.x >= o) ? sh[threadIdx.x - o] : 0;
    __syncthreads();
    sh[threadIdx.x] += t;
    __syncthreads();
  }
  if (i < N) {
    int r = csum[blockIdx.x] + sh[threadIdx.x] - v;
    rp[i] = r;
    wp[i] = r;
  }
  if (blockIdx.x == 0 && threadIdx.x == 0) rp[N] = E;
}

// Phase A: append (src,dst) at bucket tails — writes cluster on ~391 hot lines.
__global__ void bucket_scatter(const int* __restrict__ src, const int* __restrict__ dst,
                               int* __restrict__ bpos, int2* __restrict__ be, int E) {
  int e = blockIdx.x * blockDim.x + threadIdx.x;
  if (e < E) {
    int s = src[e];
    int d = dst[e];
    int p = atomicAdd(bpos + (d >> 7), 1);
    be[p] = make_int2(s, d);
  }
}

// Phase B: stream bucketed pairs; COL writes now fall in ~16KB L2-resident
// regions per bucket.
__global__ void final_scatter(const int2* __restrict__ be, int* __restrict__ wp,
                              int* __restrict__ col, int E) {
  int e = blockIdx.x * blockDim.x + threadIdx.x;
  if (e < E) {
    int2 sd = be[e];
    int p = atomicAdd(wp + sd.y, 1);
    col[p] = sd.x;
  }
}

// ---------------------------------------------------------------------------
// Edge softmax per dst node: one wave/node, lanes parallel over in-edges.
// Writes unnormalized p per edge (ALPHA), plus DEN and SELFP per node.
// ---------------------------------------------------------------------------
__global__ void attn_softmax(const int* __restrict__ row_ptr,
                             const int* __restrict__ col,
                             const float* __restrict__ es,
                             const float* __restrict__ ed,
                             float* __restrict__ alpha,
                             float* __restrict__ den_out,
                             float* __restrict__ selfp_out, int N) {
  const int lane = threadIdx.x & 63;
  const int n = blockIdx.x * (blockDim.x >> 6) + (threadIdx.x >> 6);
  if (n >= N) return;

  const int k0 = row_ptr[n];
  const int k1 = row_ptr[n + 1];
  const int deg = k1 - k0;
  const float edd = ed[n];
  const float self_lg = lrelu(es[n] + edd);

  if (deg <= 64) {
    int k = k0 + lane;
    bool act = (k < k1);
    float lg = act ? lrelu(es[col[k]] + edd) : -3.0e38f;
    float m = fmaxf(wave_max(lg), self_lg);
    float p = act ? __expf(lg - m) : 0.f;
    float den = wave_sum(p);
    float sp = __expf(self_lg - m);
    den += sp;
    if (act) alpha[k] = p;
    if (lane == 0) { den_out[n] = den; selfp_out[n] = sp; }
  } else {
    float m = self_lg;
    for (int base = k0; base < k1; base += 64) {
      int k = base + lane;
      if (k < k1) {
        float lg = lrelu(es[col[k]] + edd);
        alpha[k] = lg;
        m = fmaxf(m, lg);
      }
    }
    m = wave_max(m);
    float den = 0.f;
    for (int base = k0; base < k1; base += 64) {
      int k = base + lane;
      if (k < k1) {
        float p = __expf(alpha[k] - m);
        alpha[k] = p;
        den += p;
      }
    }
    den = wave_sum(den);
    float sp = __expf(self_lg - m);
    den += sp;
    if (lane == 0) { den_out[n] = den; selfp_out[n] = sp; }
  }
}

// ---------------------------------------------------------------------------
// Lean aggregation: one wave/node; acc += p * H[src]; no exp, no rescale.
// ---------------------------------------------------------------------------
template<bool RELU>
__global__ void gat_gather128(const int* __restrict__ row_ptr,
                              const int* __restrict__ col,
                              const float* __restrict__ H,
                              const float* __restrict__ alpha,
                              const float* __restrict__ den,
                              const float* __restrict__ selfp,
                              const float* __restrict__ bias,
                              float* __restrict__ outX, int N) {
  const int lane = threadIdx.x & 63;
  const int n = blockIdx.x * (blockDim.x >> 6) + (threadIdx.x >> 6);
  if (n >= N) return;

  const float2* Hp = (const float2*)H;
  float sp = selfp[n];
  float2 hv = Hp[(size_t)n * 64 + lane];
  float ax = sp * hv.x, ay = sp * hv.y;

  const int k0 = row_ptr[n];
  const int k1 = row_ptr[n + 1];
#pragma unroll 2
  for (int k = k0; k < k1; ++k) {
    int s = col[k];
    float p = alpha[k];
    float2 h = Hp[(size_t)s * 64 + lane];
    ax += p * h.x;
    ay += p * h.y;
  }
  float inv = 1.f / den[n];
  float2 bv = ((const float2*)bias)[lane];
  float vx = ax * inv + bv.x;
  float vy = ay * inv + bv.y;
  if (RELU) { vx = fmaxf(vx, 0.f); vy = fmaxf(vy, 0.f); }
  ((float2*)outX)[(size_t)n * 64 + lane] = make_float2(vx, vy);
}

template<bool RELU>
__global__ void gat_gather64(const int* __restrict__ row_ptr,
                             const int* __restrict__ col,
                             const float* __restrict__ H,
                             const float* __restrict__ alpha,
                             const float* __restrict__ den,
                             const float* __restrict__ selfp,
                             const float* __restrict__ bias,
                             float* __restrict__ outX, int N) {
  const int lane = threadIdx.x & 63;
  const int n = blockIdx.x * (blockDim.x >> 6) + (threadIdx.x >> 6);
  if (n >= N) return;

  float acc = selfp[n] * H[(size_t)n * 64 + lane];
  const int k0 = row_ptr[n];
  const int k1 = row_ptr[n + 1];
#pragma unroll 2
  for (int k = k0; k < k1; ++k) {
    int s = col[k];
    float p = alpha[k];
    acc += p * H[(size_t)s * 64 + lane];
  }
  float v = acc / den[n] + bias[lane];
  if (RELU) v = fmaxf(v, 0.f);
  outX[(size_t)n * 64 + lane] = v;
}

// ---------------------------------------------------------------------------

extern "C" void kernel_launch(void* const* d_in, const int* in_sizes, int n_in,
                              void* d_out, int out_size, void* d_ws, size_t ws_size,
                              hipStream_t stream) {
  const int C_HID = in_sizes[3];            // 128
  const int C_FIN = in_sizes[11];           // 64
  const int C_IN  = in_sizes[2] / C_HID;    // 128
  const int N     = in_sizes[0] / C_IN;     // 50000
  const int E     = in_sizes[1] / 2;        // 1.6M

  const float* x = (const float*)d_in[0];
  const int* ei  = (const int*)d_in[1];
  const int* src = ei;
  const int* dst = ei + E;

  const float* W0  = (const float*)d_in[2];
  const float* as0 = (const float*)d_in[3];
  const float* ad0 = (const float*)d_in[4];
  const float* b0  = (const float*)d_in[5];
  const float* W1  = (const float*)d_in[6];
  const float* as1 = (const float*)d_in[7];
  const float* ad1 = (const float*)d_in[8];
  const float* b1  = (const float*)d_in[9];
  const float* W2  = (const float*)d_in[10];
  const float* as2 = (const float*)d_in[11];
  const float* ad2 = (const float*)d_in[12];
  const float* b2  = (const float*)d_in[13];

  // Workspace layout (256B aligned)
  char* base = (char*)d_ws;
  size_t off = 0;
  auto alloc = [&](size_t bytes) -> char* {
    char* p = base + off;
    off = (off + bytes + 255) & ~((size_t)255);
    return p;
  };
  const int NCH = (N + 255) / 256;
  const int NB  = (N >> 7) + 1;          // buckets of 128 dst nodes
  float* H     = (float*)alloc((size_t)N * C_HID * sizeof(float));
  float* XB    = (float*)alloc((size_t)N * C_HID * sizeof(float));
  float* ES    = (float*)alloc((size_t)N * sizeof(float));
  float* ED    = (float*)alloc((size_t)N * sizeof(float));
  float* DEN   = (float*)alloc((size_t)N * sizeof(float));
  float* SELFP = (float*)alloc((size_t)N * sizeof(float));
  float* ALPHA = (float*)alloc((size_t)E * sizeof(float));
  int*   RP    = (int*)alloc((size_t)(N + 1) * sizeof(int));
  int*   WP    = (int*)alloc((size_t)N * sizeof(int));
  int*   COL   = (int*)alloc((size_t)E * sizeof(int));
  int*   DEG   = (int*)alloc((size_t)N * sizeof(int));
  int*   CSUM  = (int*)alloc((size_t)NCH * sizeof(int));
  int*   BCNT  = (int*)alloc((size_t)NB * sizeof(int));
  int2*  BE    = (int2*)alloc((size_t)E * sizeof(int2));
  (void)ws_size;

  const int ET256 = (E + 255) / 256;
  const int wgrid = (N + 3) / 4;     // 4 waves (256 thr) per block kernels
  const int ggrid = (N + 15) / 16;   // gemm: 16 rows per block

  // ---- CSR build (once; graph shared by all 3 layers) ----
  hipMemsetAsync(DEG, 0, (size_t)N * sizeof(int), stream);
  hipMemsetAsync(BCNT, 0, (size_t)NB * sizeof(int), stream);
  count_deg_bkt<<<ET256, 256, 0, stream>>>(dst, DEG, BCNT, E);
  scan_partial<<<NCH, 256, 0, stream>>>(DEG, CSUM, N);
  scan_chunks<<<1, 256, 0, stream>>>(CSUM, NCH);
  scan_final<<<NCH, 256, 0, stream>>>(DEG, CSUM, RP, WP, N, E);
  scan_chunks<<<1, 256, 0, stream>>>(BCNT, NB);     // BCNT -> bucket cursors
  bucket_scatter<<<ET256, 256, 0, stream>>>(src, dst, BCNT, BE, E);
  final_scatter<<<ET256, 256, 0, stream>>>(BE, WP, COL, E);

  // ---- Layer 0: x -> H -> XB (relu) ----
  gemm_tiled<128, 128><<<ggrid, 256, 0, stream>>>(x, W0, H, N);
  escore<128><<<wgrid, 256, 0, stream>>>(H, as0, ad0, ES, ED, N);
  attn_softmax<<<wgrid, 256, 0, stream>>>(RP, COL, ES, ED, ALPHA, DEN, SELFP, N);
  gat_gather128<true><<<wgrid, 256, 0, stream>>>(RP, COL, H, ALPHA, DEN, SELFP, b0, XB, N);

  // ---- Layer 1: XB -> H -> XB (relu) ----
  gemm_tiled<128, 128><<<ggrid, 256, 0, stream>>>(XB, W1, H, N);
  escore<128><<<wgrid, 256, 0, stream>>>(H, as1, ad1, ES, ED, N);
  attn_softmax<<<wgrid, 256, 0, stream>>>(RP, COL, ES, ED, ALPHA, DEN, SELFP, N);
  gat_gather128<true><<<wgrid, 256, 0, stream>>>(RP, COL, H, ALPHA, DEN, SELFP, b1, XB, N);

  // ---- Layer 2: XB -> H -> d_out (no relu) ----
  gemm_tiled<128, 64><<<ggrid, 256, 0, stream>>>(XB, W2, H, N);
  escore<64><<<wgrid, 256, 0, stream>>>(H, as2, ad2, ES, ED, N);
  attn_softmax<<<wgrid, 256, 0, stream>>>(RP, COL, ES, ED, ALPHA, DEN, SELFP, N);
  gat_gather64<false><<<wgrid, 256, 0, stream>>>(RP, COL, H, ALPHA, DEN, SELFP, b2,
                                                 (float*)d_out, N);
  (void)out_size; (void)n_in;
}

// Round 8
// 795.596 us; speedup vs baseline: 2.3458x; 2.3458x over previous
//
#include <hip/hip_runtime.h>
#include <hip/hip_bf16.h>

#define DEVFN __device__ __forceinline__

DEVFN float lrelu(float v) { return (v >= 0.f) ? v : 0.2f * v; }

DEVFN float wave_sum(float v) {
#pragma unroll
  for (int o = 1; o < 64; o <<= 1) v += __shfl_xor(v, o, 64);
  return v;
}
DEVFN float wave_max(float v) {
#pragma unroll
  for (int o = 1; o < 64; o <<= 1) v = fmaxf(v, __shfl_xor(v, o, 64));
  return v;
}

// ---------------------------------------------------------------------------
// Tiled GEMM H = X @ W.  K=128 fixed; C in {64,128}. ROWS=16 rows per block,
// 256 threads. W fully staged in LDS (K*C floats), X tile staged too.
// ---------------------------------------------------------------------------
template<int K, int C>
__global__ __launch_bounds__(256) void gemm_tiled(const float* __restrict__ X,
                                                  const float* __restrict__ W,
                                                  float* __restrict__ H, int N) {
  constexpr int ROWS = 16;
  constexpr int TM = ROWS / (256 / C);   // 8 for C=128, 4 for C=64
  __shared__ float Ws[K * C];
  __shared__ float Xs[ROWS * K];

  const int t = threadIdx.x;
  const int row0 = blockIdx.x * ROWS;
  const int nrow = min(ROWS, N - row0);

  const float4* Wv = (const float4*)W;
#pragma unroll 4
  for (int i = t; i < K * C / 4; i += 256) ((float4*)Ws)[i] = Wv[i];
  const float4* Xv = (const float4*)(X + (size_t)row0 * K);
  const int xcnt = nrow * K / 4;
  for (int i = t; i < xcnt; i += 256) ((float4*)Xs)[i] = Xv[i];
  __syncthreads();

  const int c = t % C;
  const int g = t / C;
  float acc[TM];
#pragma unroll
  for (int r = 0; r < TM; ++r) acc[r] = 0.f;

#pragma unroll 2
  for (int k = 0; k < K; k += 4) {
    float w0 = Ws[(k + 0) * C + c];
    float w1 = Ws[(k + 1) * C + c];
    float w2 = Ws[(k + 2) * C + c];
    float w3 = Ws[(k + 3) * C + c];
#pragma unroll
    for (int r = 0; r < TM; ++r) {
      float4 xv = *(const float4*)&Xs[(g * TM + r) * K + k];
      acc[r] += xv.x * w0 + xv.y * w1 + xv.z * w2 + xv.w * w3;
    }
  }
#pragma unroll
  for (int r = 0; r < TM; ++r) {
    int row = g * TM + r;
    if (row < nrow) H[(size_t)(row0 + row) * C + c] = acc[r];
  }
}

// ---------------------------------------------------------------------------
// Attention scores per node: es = h . a_src, ed = h . a_dst. One wave/node.
// ---------------------------------------------------------------------------
template<int C>
__global__ void escore(const float* __restrict__ H,
                       const float* __restrict__ a_src,
                       const float* __restrict__ a_dst,
                       float* __restrict__ es, float* __restrict__ ed, int N) {
  const int lane = threadIdx.x & 63;
  const int n = blockIdx.x * (blockDim.x >> 6) + (threadIdx.x >> 6);
  if (n >= N) return;
  float ps, pd;
  if (C == 128) {
    float2 h = ((const float2*)H)[(size_t)n * 64 + lane];
    float2 as_ = ((const float2*)a_src)[lane];
    float2 ad_ = ((const float2*)a_dst)[lane];
    ps = h.x * as_.x + h.y * as_.y;
    pd = h.x * ad_.x + h.y * ad_.y;
  } else {
    float h = H[(size_t)n * C + lane];
    ps = h * a_src[lane];
    pd = h * a_dst[lane];
  }
  ps = wave_sum(ps);
  pd = wave_sum(pd);
  if (lane == 0) { es[n] = ps; ed[n] = pd; }
}

// ---------------------------------------------------------------------------
// CSR build: histogram -> parallel 3-phase scan -> ranged multi-pass scatter.
// ---------------------------------------------------------------------------
__global__ void csr_count(const int* __restrict__ dst, int* __restrict__ deg, int E) {
  int e = blockIdx.x * blockDim.x + threadIdx.x;
  if (e < E) atomicAdd(deg + dst[e], 1);
}

__global__ void scan_partial(const int* __restrict__ deg, int* __restrict__ csum, int N) {
  __shared__ int sh[256];
  int i = blockIdx.x * 256 + threadIdx.x;
  sh[threadIdx.x] = (i < N) ? deg[i] : 0;
  __syncthreads();
  for (int o = 128; o > 0; o >>= 1) {
    if (threadIdx.x < o) sh[threadIdx.x] += sh[threadIdx.x + o];
    __syncthreads();
  }
  if (threadIdx.x == 0) csum[blockIdx.x] = sh[0];
}

__global__ void scan_chunks(int* __restrict__ csum, int nch) {
  __shared__ int sh[256];
  __shared__ int carry;
  if (threadIdx.x == 0) carry = 0;
  __syncthreads();
  for (int base = 0; base < nch; base += 256) {
    int i = base + threadIdx.x;
    int v = (i < nch) ? csum[i] : 0;
    sh[threadIdx.x] = v;
    __syncthreads();
    for (int o = 1; o < 256; o <<= 1) {
      int t = (threadIdx.x >= o) ? sh[threadIdx.x - o] : 0;
      __syncthreads();
      sh[threadIdx.x] += t;
      __syncthreads();
    }
    if (i < nch) csum[i] = carry + sh[threadIdx.x] - v;
    __syncthreads();
    if (threadIdx.x == 255) carry += sh[255];
    __syncthreads();
  }
}

__global__ void scan_final(const int* __restrict__ deg, const int* __restrict__ csum,
                           int* __restrict__ rp, int* __restrict__ wp, int N, int E) {
  __shared__ int sh[256];
  int i = blockIdx.x * 256 + threadIdx.x;
  int v = (i < N) ? deg[i] : 0;
  sh[threadIdx.x] = v;
  __syncthreads();
  for (int o = 1; o < 256; o <<= 1) {
    int t = (threadIdx.x >= o) ? sh[threadIdx.x - o] : 0;
    __syncthreads();
    sh[threadIdx.x] += t;
    __syncthreads();
  }
  if (i < N) {
    int r = csum[blockIdx.x] + sh[threadIdx.x] - v;
    rp[i] = r;
    wp[i] = r;
  }
  if (blockIdx.x == 0 && threadIdx.x == 0) rp[N] = E;
}

// Ranged multi-pass scatter: pass j handles dst in [j*range, (j+1)*range).
// COL writes per pass fall in an ~800KB L2-resident region (flushed once)
// instead of randomly over 6.4MB. wp atomics stay on 50000 distributed
// counters (no contention). src/dst re-reads hit L2 after pass 0.
__global__ void csr_scatter_ranged(const int* __restrict__ src,
                                   const int* __restrict__ dst,
                                   int* __restrict__ wp, int* __restrict__ col,
                                   int E, int range, int npass) {
  const int stride = gridDim.x * blockDim.x;
  const int gid = blockIdx.x * blockDim.x + threadIdx.x;
  for (int pass = 0; pass < npass; ++pass) {
    const int lo = pass * range;
    const int hi = lo + range;
    for (int e = gid; e < E; e += stride) {
      int d = dst[e];
      if (d >= lo && d < hi) {
        int p = atomicAdd(wp + d, 1);
        col[p] = src[e];
      }
    }
  }
}

// ---------------------------------------------------------------------------
// Edge softmax per dst node: one wave/node, lanes parallel over in-edges.
// Writes unnormalized p per edge (ALPHA), plus DEN and SELFP per node.
// ---------------------------------------------------------------------------
__global__ void attn_softmax(const int* __restrict__ row_ptr,
                             const int* __restrict__ col,
                             const float* __restrict__ es,
                             const float* __restrict__ ed,
                             float* __restrict__ alpha,
                             float* __restrict__ den_out,
                             float* __restrict__ selfp_out, int N) {
  const int lane = threadIdx.x & 63;
  const int n = blockIdx.x * (blockDim.x >> 6) + (threadIdx.x >> 6);
  if (n >= N) return;

  const int k0 = row_ptr[n];
  const int k1 = row_ptr[n + 1];
  const int deg = k1 - k0;
  const float edd = ed[n];
  const float self_lg = lrelu(es[n] + edd);

  if (deg <= 64) {
    int k = k0 + lane;
    bool act = (k < k1);
    float lg = act ? lrelu(es[col[k]] + edd) : -3.0e38f;
    float m = fmaxf(wave_max(lg), self_lg);
    float p = act ? __expf(lg - m) : 0.f;
    float den = wave_sum(p);
    float sp = __expf(self_lg - m);
    den += sp;
    if (act) alpha[k] = p;
    if (lane == 0) { den_out[n] = den; selfp_out[n] = sp; }
  } else {
    float m = self_lg;
    for (int base = k0; base < k1; base += 64) {
      int k = base + lane;
      if (k < k1) {
        float lg = lrelu(es[col[k]] + edd);
        alpha[k] = lg;
        m = fmaxf(m, lg);
      }
    }
    m = wave_max(m);
    float den = 0.f;
    for (int base = k0; base < k1; base += 64) {
      int k = base + lane;
      if (k < k1) {
        float p = __expf(alpha[k] - m);
        alpha[k] = p;
        den += p;
      }
    }
    den = wave_sum(den);
    float sp = __expf(self_lg - m);
    den += sp;
    if (lane == 0) { den_out[n] = den; selfp_out[n] = sp; }
  }
}

// ---------------------------------------------------------------------------
// Lean aggregation: one wave/node; acc += p * H[src]; no exp, no rescale.
// ---------------------------------------------------------------------------
template<bool RELU>
__global__ void gat_gather128(const int* __restrict__ row_ptr,
                              const int* __restrict__ col,
                              const float* __restrict__ H,
                              const float* __restrict__ alpha,
                              const float* __restrict__ den,
                              const float* __restrict__ selfp,
                              const float* __restrict__ bias,
                              float* __restrict__ outX, int N) {
  const int lane = threadIdx.x & 63;
  const int n = blockIdx.x * (blockDim.x >> 6) + (threadIdx.x >> 6);
  if (n >= N) return;

  const float2* Hp = (const float2*)H;
  float sp = selfp[n];
  float2 hv = Hp[(size_t)n * 64 + lane];
  float ax = sp * hv.x, ay = sp * hv.y;

  const int k0 = row_ptr[n];
  const int k1 = row_ptr[n + 1];
#pragma unroll 2
  for (int k = k0; k < k1; ++k) {
    int s = col[k];
    float p = alpha[k];
    float2 h = Hp[(size_t)s * 64 + lane];
    ax += p * h.x;
    ay += p * h.y;
  }
  float inv = 1.f / den[n];
  float2 bv = ((const float2*)bias)[lane];
  float vx = ax * inv + bv.x;
  float vy = ay * inv + bv.y;
  if (RELU) { vx = fmaxf(vx, 0.f); vy = fmaxf(vy, 0.f); }
  ((float2*)outX)[(size_t)n * 64 + lane] = make_float2(vx, vy);
}

template<bool RELU>
__global__ void gat_gather64(const int* __restrict__ row_ptr,
                             const int* __restrict__ col,
                             const float* __restrict__ H,
                             const float* __restrict__ alpha,
                             const float* __restrict__ den,
                             const float* __restrict__ selfp,
                             const float* __restrict__ bias,
                             float* __restrict__ outX, int N) {
  const int lane = threadIdx.x & 63;
  const int n = blockIdx.x * (blockDim.x >> 6) + (threadIdx.x >> 6);
  if (n >= N) return;

  float acc = selfp[n] * H[(size_t)n * 64 + lane];
  const int k0 = row_ptr[n];
  const int k1 = row_ptr[n + 1];
#pragma unroll 2
  for (int k = k0; k < k1; ++k) {
    int s = col[k];
    float p = alpha[k];
    acc += p * H[(size_t)s * 64 + lane];
  }
  float v = acc / den[n] + bias[lane];
  if (RELU) v = fmaxf(v, 0.f);
  outX[(size_t)n * 64 + lane] = v;
}

// ---------------------------------------------------------------------------

extern "C" void kernel_launch(void* const* d_in, const int* in_sizes, int n_in,
                              void* d_out, int out_size, void* d_ws, size_t ws_size,
                              hipStream_t stream) {
  const int C_HID = in_sizes[3];            // 128
  const int C_FIN = in_sizes[11];           // 64
  const int C_IN  = in_sizes[2] / C_HID;    // 128
  const int N     = in_sizes[0] / C_IN;     // 50000
  const int E     = in_sizes[1] / 2;        // 1.6M

  const float* x = (const float*)d_in[0];
  const int* ei  = (const int*)d_in[1];
  const int* src = ei;
  const int* dst = ei + E;

  const float* W0  = (const float*)d_in[2];
  const float* as0 = (const float*)d_in[3];
  const float* ad0 = (const float*)d_in[4];
  const float* b0  = (const float*)d_in[5];
  const float* W1  = (const float*)d_in[6];
  const float* as1 = (const float*)d_in[7];
  const float* ad1 = (const float*)d_in[8];
  const float* b1  = (const float*)d_in[9];
  const float* W2  = (const float*)d_in[10];
  const float* as2 = (const float*)d_in[11];
  const float* ad2 = (const float*)d_in[12];
  const float* b2  = (const float*)d_in[13];

  // Workspace layout (256B aligned)
  char* base = (char*)d_ws;
  size_t off = 0;
  auto alloc = [&](size_t bytes) -> char* {
    char* p = base + off;
    off = (off + bytes + 255) & ~((size_t)255);
    return p;
  };
  const int NCH = (N + 255) / 256;
  float* H     = (float*)alloc((size_t)N * C_HID * sizeof(float));
  float* XB    = (float*)alloc((size_t)N * C_HID * sizeof(float));
  float* ES    = (float*)alloc((size_t)N * sizeof(float));
  float* ED    = (float*)alloc((size_t)N * sizeof(float));
  float* DEN   = (float*)alloc((size_t)N * sizeof(float));
  float* SELFP = (float*)alloc((size_t)N * sizeof(float));
  float* ALPHA = (float*)alloc((size_t)E * sizeof(float));
  int*   RP    = (int*)alloc((size_t)(N + 1) * sizeof(int));
  int*   WP    = (int*)alloc((size_t)N * sizeof(int));
  int*   COL   = (int*)alloc((size_t)E * sizeof(int));
  int*   DEG   = (int*)alloc((size_t)N * sizeof(int));
  int*   CSUM  = (int*)alloc((size_t)NCH * sizeof(int));
  (void)ws_size;

  const int ET256 = (E + 255) / 256;
  const int wgrid = (N + 3) / 4;     // 4 waves (256 thr) per block kernels
  const int ggrid = (N + 15) / 16;   // gemm: 16 rows per block

  // ---- CSR build (once; graph shared by all 3 layers) ----
  hipMemsetAsync(DEG, 0, (size_t)N * sizeof(int), stream);
  csr_count<<<ET256, 256, 0, stream>>>(dst, DEG, E);
  scan_partial<<<NCH, 256, 0, stream>>>(DEG, CSUM, N);
  scan_chunks<<<1, 256, 0, stream>>>(CSUM, NCH);
  scan_final<<<NCH, 256, 0, stream>>>(DEG, CSUM, RP, WP, N, E);
  {
    const int NPASS = 8;
    const int range = (N + NPASS - 1) / NPASS;   // ~6250 nodes -> ~800KB COL
    csr_scatter_ranged<<<2048, 256, 0, stream>>>(src, dst, WP, COL, E, range, NPASS);
  }

  // ---- Layer 0: x -> H -> XB (relu) ----
  gemm_tiled<128, 128><<<ggrid, 256, 0, stream>>>(x, W0, H, N);
  escore<128><<<wgrid, 256, 0, stream>>>(H, as0, ad0, ES, ED, N);
  attn_softmax<<<wgrid, 256, 0, stream>>>(RP, COL, ES, ED, ALPHA, DEN, SELFP, N);
  gat_gather128<true><<<wgrid, 256, 0, stream>>>(RP, COL, H, ALPHA, DEN, SELFP, b0, XB, N);

  // ---- Layer 1: XB -> H -> XB (relu) ----
  gemm_tiled<128, 128><<<ggrid, 256, 0, stream>>>(XB, W1, H, N);
  escore<128><<<wgrid, 256, 0, stream>>>(H, as1, ad1, ES, ED, N);
  attn_softmax<<<wgrid, 256, 0, stream>>>(RP, COL, ES, ED, ALPHA, DEN, SELFP, N);
  gat_gather128<true><<<wgrid, 256, 0, stream>>>(RP, COL, H, ALPHA, DEN, SELFP, b1, XB, N);

  // ---- Layer 2: XB -> H -> d_out (no relu) ----
  gemm_tiled<128, 64><<<ggrid, 256, 0, stream>>>(XB, W2, H, N);
  escore<64><<<wgrid, 256, 0, stream>>>(H, as2, ad2, ES, ED, N);
  attn_softmax<<<wgrid, 256, 0, stream>>>(RP, COL, ES, ED, ALPHA, DEN, SELFP, N);
  gat_gather64<false><<<wgrid, 256, 0, stream>>>(RP, COL, H, ALPHA, DEN, SELFP, b2,
                                                 (float*)d_out, N);
  (void)out_size; (void)n_in;
}

// Round 9
// 646.676 us; speedup vs baseline: 2.8860x; 1.2303x over previous
//
#include <hip/hip_runtime.h>
#include <hip/hip_bf16.h>

#define DEVFN __device__ __forceinline__

DEVFN float lrelu(float v) { return (v >= 0.f) ? v : 0.2f * v; }

// packed bf16x2 (uint) -> 2 floats; elem0 = low 16 bits
DEVFN float2 bf2x2(unsigned u) {
  return make_float2(__uint_as_float(u << 16), __uint_as_float(u & 0xFFFF0000u));
}
DEVFN float bf1(unsigned short b) { return __uint_as_float(((unsigned)b) << 16); }

DEVFN float wave_sum(float v) {
#pragma unroll
  for (int o = 1; o < 64; o <<= 1) v += __shfl_xor(v, o, 64);
  return v;
}
DEVFN float wave_max(float v) {
#pragma unroll
  for (int o = 1; o < 64; o <<= 1) v = fmaxf(v, __shfl_xor(v, o, 64));
  return v;
}

// ---------------------------------------------------------------------------
// Tiled GEMM H = X @ W (fp32 in, bf16 out).  K=128; C in {64,128}.
// ROWS=16 rows/block, 256 threads. W staged in LDS.
// ---------------------------------------------------------------------------
template<int K, int C>
__global__ __launch_bounds__(256) void gemm_tiled(const float* __restrict__ X,
                                                  const float* __restrict__ W,
                                                  __hip_bfloat16* __restrict__ H,
                                                  int N) {
  constexpr int ROWS = 16;
  constexpr int TM = ROWS / (256 / C);   // 8 for C=128, 4 for C=64
  __shared__ float Ws[K * C];
  __shared__ float Xs[ROWS * K];

  const int t = threadIdx.x;
  const int row0 = blockIdx.x * ROWS;
  const int nrow = min(ROWS, N - row0);

  const float4* Wv = (const float4*)W;
#pragma unroll 4
  for (int i = t; i < K * C / 4; i += 256) ((float4*)Ws)[i] = Wv[i];
  const float4* Xv = (const float4*)(X + (size_t)row0 * K);
  const int xcnt = nrow * K / 4;
  for (int i = t; i < xcnt; i += 256) ((float4*)Xs)[i] = Xv[i];
  __syncthreads();

  const int c = t % C;
  const int g = t / C;
  float acc[TM];
#pragma unroll
  for (int r = 0; r < TM; ++r) acc[r] = 0.f;

#pragma unroll 2
  for (int k = 0; k < K; k += 4) {
    float w0 = Ws[(k + 0) * C + c];
    float w1 = Ws[(k + 1) * C + c];
    float w2 = Ws[(k + 2) * C + c];
    float w3 = Ws[(k + 3) * C + c];
#pragma unroll
    for (int r = 0; r < TM; ++r) {
      float4 xv = *(const float4*)&Xs[(g * TM + r) * K + k];
      acc[r] += xv.x * w0 + xv.y * w1 + xv.z * w2 + xv.w * w3;
    }
  }
#pragma unroll
  for (int r = 0; r < TM; ++r) {
    int row = g * TM + r;
    if (row < nrow) H[(size_t)(row0 + row) * C + c] = __float2bfloat16(acc[r]);
  }
}

// ---------------------------------------------------------------------------
// Attention scores per node from bf16 H: es = h.a_src, ed = h.a_dst.
// ---------------------------------------------------------------------------
template<int C>
__global__ void escore(const __hip_bfloat16* __restrict__ H,
                       const float* __restrict__ a_src,
                       const float* __restrict__ a_dst,
                       float* __restrict__ es, float* __restrict__ ed, int N) {
  const int lane = threadIdx.x & 63;
  const int n = blockIdx.x * (blockDim.x >> 6) + (threadIdx.x >> 6);
  if (n >= N) return;
  float ps, pd;
  if (C == 128) {
    float2 h = bf2x2(((const unsigned*)H)[(size_t)n * 64 + lane]);
    float2 as_ = ((const float2*)a_src)[lane];
    float2 ad_ = ((const float2*)a_dst)[lane];
    ps = h.x * as_.x + h.y * as_.y;
    pd = h.x * ad_.x + h.y * ad_.y;
  } else {
    float h = bf1(((const unsigned short*)H)[(size_t)n * C + lane]);
    ps = h * a_src[lane];
    pd = h * a_dst[lane];
  }
  ps = wave_sum(ps);
  pd = wave_sum(pd);
  if (lane == 0) { es[n] = ps; ed[n] = pd; }
}

// ---------------------------------------------------------------------------
// CSR build: histogram -> parallel 3-phase scan -> ranged multi-pass scatter.
// ---------------------------------------------------------------------------
__global__ void csr_count(const int* __restrict__ dst, int* __restrict__ deg, int E) {
  int e = blockIdx.x * blockDim.x + threadIdx.x;
  if (e < E) atomicAdd(deg + dst[e], 1);
}

__global__ void scan_partial(const int* __restrict__ deg, int* __restrict__ csum, int N) {
  __shared__ int sh[256];
  int i = blockIdx.x * 256 + threadIdx.x;
  sh[threadIdx.x] = (i < N) ? deg[i] : 0;
  __syncthreads();
  for (int o = 128; o > 0; o >>= 1) {
    if (threadIdx.x < o) sh[threadIdx.x] += sh[threadIdx.x + o];
    __syncthreads();
  }
  if (threadIdx.x == 0) csum[blockIdx.x] = sh[0];
}

__global__ void scan_chunks(int* __restrict__ csum, int nch) {
  __shared__ int sh[256];
  __shared__ int carry;
  if (threadIdx.x == 0) carry = 0;
  __syncthreads();
  for (int base = 0; base < nch; base += 256) {
    int i = base + threadIdx.x;
    int v = (i < nch) ? csum[i] : 0;
    sh[threadIdx.x] = v;
    __syncthreads();
    for (int o = 1; o < 256; o <<= 1) {
      int t = (threadIdx.x >= o) ? sh[threadIdx.x - o] : 0;
      __syncthreads();
      sh[threadIdx.x] += t;
      __syncthreads();
    }
    if (i < nch) csum[i] = carry + sh[threadIdx.x] - v;
    __syncthreads();
    if (threadIdx.x == 255) carry += sh[255];
    __syncthreads();
  }
}

__global__ void scan_final(const int* __restrict__ deg, const int* __restrict__ csum,
                           int* __restrict__ rp, int* __restrict__ wp, int N, int E) {
  __shared__ int sh[256];
  int i = blockIdx.x * 256 + threadIdx.x;
  int v = (i < N) ? deg[i] : 0;
  sh[threadIdx.x] = v;
  __syncthreads();
  for (int o = 1; o < 256; o <<= 1) {
    int t = (threadIdx.x >= o) ? sh[threadIdx.x - o] : 0;
    __syncthreads();
    sh[threadIdx.x] += t;
    __syncthreads();
  }
  if (i < N) {
    int r = csum[blockIdx.x] + sh[threadIdx.x] - v;
    rp[i] = r;
    wp[i] = r;
  }
  if (blockIdx.x == 0 && threadIdx.x == 0) rp[N] = E;
}

// Ranged multi-pass scatter: pass j handles dst in [j*range,(j+1)*range).
__global__ void csr_scatter_ranged(const int* __restrict__ src,
                                   const int* __restrict__ dst,
                                   int* __restrict__ wp, int* __restrict__ col,
                                   int E, int range, int npass) {
  const int stride = gridDim.x * blockDim.x;
  const int gid = blockIdx.x * blockDim.x + threadIdx.x;
  for (int pass = 0; pass < npass; ++pass) {
    const int lo = pass * range;
    const int hi = lo + range;
    for (int e = gid; e < E; e += stride) {
      int d = dst[e];
      if (d >= lo && d < hi) {
        int p = atomicAdd(wp + d, 1);
        col[p] = src[e];
      }
    }
  }
}

// ---------------------------------------------------------------------------
// Edge softmax per dst node (unchanged).
// ---------------------------------------------------------------------------
__global__ void attn_softmax(const int* __restrict__ row_ptr,
                             const int* __restrict__ col,
                             const float* __restrict__ es,
                             const float* __restrict__ ed,
                             float* __restrict__ alpha,
                             float* __restrict__ den_out,
                             float* __restrict__ selfp_out, int N) {
  const int lane = threadIdx.x & 63;
  const int n = blockIdx.x * (blockDim.x >> 6) + (threadIdx.x >> 6);
  if (n >= N) return;

  const int k0 = row_ptr[n];
  const int k1 = row_ptr[n + 1];
  const int deg = k1 - k0;
  const float edd = ed[n];
  const float self_lg = lrelu(es[n] + edd);

  if (deg <= 64) {
    int k = k0 + lane;
    bool act = (k < k1);
    float lg = act ? lrelu(es[col[k]] + edd) : -3.0e38f;
    float m = fmaxf(wave_max(lg), self_lg);
    float p = act ? __expf(lg - m) : 0.f;
    float den = wave_sum(p);
    float sp = __expf(self_lg - m);
    den += sp;
    if (act) alpha[k] = p;
    if (lane == 0) { den_out[n] = den; selfp_out[n] = sp; }
  } else {
    float m = self_lg;
    for (int base = k0; base < k1; base += 64) {
      int k = base + lane;
      if (k < k1) {
        float lg = lrelu(es[col[k]] + edd);
        alpha[k] = lg;
        m = fmaxf(m, lg);
      }
    }
    m = wave_max(m);
    float den = 0.f;
    for (int base = k0; base < k1; base += 64) {
      int k = base + lane;
      if (k < k1) {
        float p = __expf(alpha[k] - m);
        alpha[k] = p;
        den += p;
      }
    }
    den = wave_sum(den);
    float sp = __expf(self_lg - m);
    den += sp;
    if (lane == 0) { den_out[n] = den; selfp_out[n] = sp; }
  }
}

// ---------------------------------------------------------------------------
// Lean aggregation from bf16 H: one wave/node, 4-edge batches (4 rows in
// flight per wave). fp32 accumulate, bias (+ReLU) fused, fp32 out.
// ---------------------------------------------------------------------------
template<bool RELU>
__global__ void gat_gather128(const int* __restrict__ row_ptr,
                              const int* __restrict__ col,
                              const __hip_bfloat16* __restrict__ H,
                              const float* __restrict__ alpha,
                              const float* __restrict__ den,
                              const float* __restrict__ selfp,
                              const float* __restrict__ bias,
                              float* __restrict__ outX, int N) {
  const int lane = threadIdx.x & 63;
  const int n = blockIdx.x * (blockDim.x >> 6) + (threadIdx.x >> 6);
  if (n >= N) return;

  const unsigned* Hp = (const unsigned*)H;   // bf16x2 per lane
  float sp = selfp[n];
  float2 hv = bf2x2(Hp[(size_t)n * 64 + lane]);
  float ax0 = sp * hv.x, ay0 = sp * hv.y;
  float ax1 = 0.f, ay1 = 0.f;

  const int k0 = row_ptr[n];
  const int k1 = row_ptr[n + 1];
  int k = k0;
  for (; k + 4 <= k1; k += 4) {
    int s0 = col[k + 0], s1 = col[k + 1], s2 = col[k + 2], s3 = col[k + 3];
    float p0 = alpha[k + 0], p1 = alpha[k + 1], p2 = alpha[k + 2], p3 = alpha[k + 3];
    unsigned u0 = Hp[(size_t)s0 * 64 + lane];
    unsigned u1 = Hp[(size_t)s1 * 64 + lane];
    unsigned u2 = Hp[(size_t)s2 * 64 + lane];
    unsigned u3 = Hp[(size_t)s3 * 64 + lane];
    float2 h0 = bf2x2(u0), h1 = bf2x2(u1), h2 = bf2x2(u2), h3 = bf2x2(u3);
    ax0 += p0 * h0.x; ay0 += p0 * h0.y;
    ax1 += p1 * h1.x; ay1 += p1 * h1.y;
    ax0 += p2 * h2.x; ay0 += p2 * h2.y;
    ax1 += p3 * h3.x; ay1 += p3 * h3.y;
  }
  for (; k < k1; ++k) {
    int s = col[k];
    float p = alpha[k];
    float2 h = bf2x2(Hp[(size_t)s * 64 + lane]);
    ax0 += p * h.x; ay0 += p * h.y;
  }
  float inv = 1.f / den[n];
  float2 bv = ((const float2*)bias)[lane];
  float vx = (ax0 + ax1) * inv + bv.x;
  float vy = (ay0 + ay1) * inv + bv.y;
  if (RELU) { vx = fmaxf(vx, 0.f); vy = fmaxf(vy, 0.f); }
  ((float2*)outX)[(size_t)n * 64 + lane] = make_float2(vx, vy);
}

template<bool RELU>
__global__ void gat_gather64(const int* __restrict__ row_ptr,
                             const int* __restrict__ col,
                             const __hip_bfloat16* __restrict__ H,
                             const float* __restrict__ alpha,
                             const float* __restrict__ den,
                             const float* __restrict__ selfp,
                             const float* __restrict__ bias,
                             float* __restrict__ outX, int N) {
  const int lane = threadIdx.x & 63;
  const int n = blockIdx.x * (blockDim.x >> 6) + (threadIdx.x >> 6);
  if (n >= N) return;

  const unsigned short* Hp = (const unsigned short*)H;
  float a0 = selfp[n] * bf1(Hp[(size_t)n * 64 + lane]);
  float a1 = 0.f;
  const int k0 = row_ptr[n];
  const int k1 = row_ptr[n + 1];
  int k = k0;
  for (; k + 4 <= k1; k += 4) {
    int s0 = col[k + 0], s1 = col[k + 1], s2 = col[k + 2], s3 = col[k + 3];
    float p0 = alpha[k + 0], p1 = alpha[k + 1], p2 = alpha[k + 2], p3 = alpha[k + 3];
    unsigned short u0 = Hp[(size_t)s0 * 64 + lane];
    unsigned short u1 = Hp[(size_t)s1 * 64 + lane];
    unsigned short u2 = Hp[(size_t)s2 * 64 + lane];
    unsigned short u3 = Hp[(size_t)s3 * 64 + lane];
    a0 += p0 * bf1(u0); a1 += p1 * bf1(u1);
    a0 += p2 * bf1(u2); a1 += p3 * bf1(u3);
  }
  for (; k < k1; ++k) {
    a0 += alpha[k] * bf1(Hp[(size_t)col[k] * 64 + lane]);
  }
  float v = (a0 + a1) / den[n] + bias[lane];
  if (RELU) v = fmaxf(v, 0.f);
  outX[(size_t)n * 64 + lane] = v;
}

// ---------------------------------------------------------------------------

extern "C" void kernel_launch(void* const* d_in, const int* in_sizes, int n_in,
                              void* d_out, int out_size, void* d_ws, size_t ws_size,
                              hipStream_t stream) {
  const int C_HID = in_sizes[3];            // 128
  const int C_FIN = in_sizes[11];           // 64
  const int C_IN  = in_sizes[2] / C_HID;    // 128
  const int N     = in_sizes[0] / C_IN;     // 50000
  const int E     = in_sizes[1] / 2;        // 1.6M

  const float* x = (const float*)d_in[0];
  const int* ei  = (const int*)d_in[1];
  const int* src = ei;
  const int* dst = ei + E;

  const float* W0  = (const float*)d_in[2];
  const float* as0 = (const float*)d_in[3];
  const float* ad0 = (const float*)d_in[4];
  const float* b0  = (const float*)d_in[5];
  const float* W1  = (const float*)d_in[6];
  const float* as1 = (const float*)d_in[7];
  const float* ad1 = (const float*)d_in[8];
  const float* b1  = (const float*)d_in[9];
  const float* W2  = (const float*)d_in[10];
  const float* as2 = (const float*)d_in[11];
  const float* ad2 = (const float*)d_in[12];
  const float* b2  = (const float*)d_in[13];

  // Workspace layout (256B aligned)
  char* base = (char*)d_ws;
  size_t off = 0;
  auto alloc = [&](size_t bytes) -> char* {
    char* p = base + off;
    off = (off + bytes + 255) & ~((size_t)255);
    return p;
  };
  const int NCH = (N + 255) / 256;
  __hip_bfloat16* H = (__hip_bfloat16*)alloc((size_t)N * C_HID * sizeof(__hip_bfloat16));
  float* XB    = (float*)alloc((size_t)N * C_HID * sizeof(float));
  float* ES    = (float*)alloc((size_t)N * sizeof(float));
  float* ED    = (float*)alloc((size_t)N * sizeof(float));
  float* DEN   = (float*)alloc((size_t)N * sizeof(float));
  float* SELFP = (float*)alloc((size_t)N * sizeof(float));
  float* ALPHA = (float*)alloc((size_t)E * sizeof(float));
  int*   RP    = (int*)alloc((size_t)(N + 1) * sizeof(int));
  int*   WP    = (int*)alloc((size_t)N * sizeof(int));
  int*   COL   = (int*)alloc((size_t)E * sizeof(int));
  int*   DEG   = (int*)alloc((size_t)N * sizeof(int));
  int*   CSUM  = (int*)alloc((size_t)NCH * sizeof(int));
  (void)ws_size;

  const int ET256 = (E + 255) / 256;
  const int wgrid = (N + 3) / 4;     // 4 waves (256 thr) per block kernels
  const int ggrid = (N + 15) / 16;   // gemm: 16 rows per block

  // ---- CSR build (once; graph shared by all 3 layers) ----
  hipMemsetAsync(DEG, 0, (size_t)N * sizeof(int), stream);
  csr_count<<<ET256, 256, 0, stream>>>(dst, DEG, E);
  scan_partial<<<NCH, 256, 0, stream>>>(DEG, CSUM, N);
  scan_chunks<<<1, 256, 0, stream>>>(CSUM, NCH);
  scan_final<<<NCH, 256, 0, stream>>>(DEG, CSUM, RP, WP, N, E);
  {
    const int NPASS = 8;
    const int range = (N + NPASS - 1) / NPASS;
    csr_scatter_ranged<<<2048, 256, 0, stream>>>(src, dst, WP, COL, E, range, NPASS);
  }

  // ---- Layer 0: x -> H -> XB (relu) ----
  gemm_tiled<128, 128><<<ggrid, 256, 0, stream>>>(x, W0, H, N);
  escore<128><<<wgrid, 256, 0, stream>>>(H, as0, ad0, ES, ED, N);
  attn_softmax<<<wgrid, 256, 0, stream>>>(RP, COL, ES, ED, ALPHA, DEN, SELFP, N);
  gat_gather128<true><<<wgrid, 256, 0, stream>>>(RP, COL, H, ALPHA, DEN, SELFP, b0, XB, N);

  // ---- Layer 1: XB -> H -> XB (relu) ----
  gemm_tiled<128, 128><<<ggrid, 256, 0, stream>>>(XB, W1, H, N);
  escore<128><<<wgrid, 256, 0, stream>>>(H, as1, ad1, ES, ED, N);
  attn_softmax<<<wgrid, 256, 0, stream>>>(RP, COL, ES, ED, ALPHA, DEN, SELFP, N);
  gat_gather128<true><<<wgrid, 256, 0, stream>>>(RP, COL, H, ALPHA, DEN, SELFP, b1, XB, N);

  // ---- Layer 2: XB -> H -> d_out (no relu) ----
  gemm_tiled<128, 64><<<ggrid, 256, 0, stream>>>(XB, W2, H, N);
  escore<64><<<wgrid, 256, 0, stream>>>(H, as2, ad2, ES, ED, N);
  attn_softmax<<<wgrid, 256, 0, stream>>>(RP, COL, ES, ED, ALPHA, DEN, SELFP, N);
  gat_gather64<false><<<wgrid, 256, 0, stream>>>(RP, COL, H, ALPHA, DEN, SELFP, b2,
                                                 (float*)d_out, N);
  (void)out_size; (void)n_in;
}

// Round 10
// 554.507 us; speedup vs baseline: 3.3657x; 1.1662x over previous
//
#include <hip/hip_runtime.h>
#include <hip/hip_bf16.h>

#define DEVFN __device__ __forceinline__

typedef __attribute__((ext_vector_type(8))) short bfrag;   // 8 bf16 (4 VGPRs)
typedef __attribute__((ext_vector_type(4))) float facc4;   // 4 fp32 acc

DEVFN float lrelu(float v) { return (v >= 0.f) ? v : 0.2f * v; }

// packed bf16x2 (uint) -> 2 floats; elem0 = low 16 bits
DEVFN float2 bf2x2(unsigned u) {
  return make_float2(__uint_as_float(u << 16), __uint_as_float(u & 0xFFFF0000u));
}
DEVFN float bf1(unsigned short b) { return __uint_as_float(((unsigned)b) << 16); }
DEVFN unsigned short f2bf(float f) {
  __hip_bfloat16 h = __float2bfloat16(f);
  return *reinterpret_cast<unsigned short*>(&h);
}
DEVFN unsigned packbf2(float x, float y) {
  return (unsigned)f2bf(x) | ((unsigned)f2bf(y) << 16);
}

DEVFN float wave_sum(float v) {
#pragma unroll
  for (int o = 1; o < 64; o <<= 1) v += __shfl_xor(v, o, 64);
  return v;
}
DEVFN float wave_max(float v) {
#pragma unroll
  for (int o = 1; o < 64; o <<= 1) v = fmaxf(v, __shfl_xor(v, o, 64));
  return v;
}

// ---------------------------------------------------------------------------
// fp32 -> bf16 conversions (X once; W transposed per layer).
// ---------------------------------------------------------------------------
__global__ void conv_x_bf16(const float* __restrict__ in,
                            unsigned short* __restrict__ out,
                            int n_valid, int n_total) {
  int i = blockIdx.x * 256 + threadIdx.x;
  if (i < n_total) out[i] = f2bf(i < n_valid ? in[i] : 0.f);
}

// WT[c][k] = bf16(W[k][c]);  K=128 fixed.
__global__ void conv_wt(const float* __restrict__ W, unsigned short* __restrict__ WT,
                        int Cc) {
  int i = blockIdx.x * 256 + threadIdx.x;
  if (i < Cc * 128) {
    int k = i & 127;
    int c = i >> 7;
    WT[i] = f2bf(W[k * Cc + c]);
  }
}

// ---------------------------------------------------------------------------
// MFMA GEMM: H[N][C] = X[N][128] @ W[128][C], bf16 in/out, fp32 accumulate.
// Block: 64 rows x C cols, 4 waves (wave w -> rows w*16..w*16+15).
// A-frag straight from global (16B/lane); B-frag from LDS-staged WT (padded).
// mfma_f32_16x16x32_bf16: A[m=lane&15][k=quad*8+j], B[k=quad*8+j][n=lane&15],
// D[row=quad*4+reg][col=lane&15]  (learn_hip m89-verified layouts).
// ---------------------------------------------------------------------------
template<int C>
__global__ __launch_bounds__(256) void gemm_mfma(const unsigned short* __restrict__ Xb,
                                                 const unsigned short* __restrict__ WT,
                                                 unsigned short* __restrict__ H,
                                                 int N) {
  constexpr int K = 128;
  constexpr int LSTR = K + 8;          // halfword stride, breaks bank alignment
  constexpr int NT = C / 16;           // col tiles
  __shared__ unsigned short WsT[C * LSTR];

  const int t = threadIdx.x;
  // stage WT (C x 128 bf16) -> LDS with padded stride; 16B per thread-iter
  {
    const int r0 = t >> 4;             // 16 rows per sweep
    const int o = (t & 15) * 8;
    for (int r = r0; r < C; r += 16) {
      *(float4*)(&WsT[r * LSTR + o]) = *(const float4*)(WT + r * K + o);
    }
  }
  __syncthreads();

  const int wave = t >> 6;
  const int lane = t & 63;
  const int l15 = lane & 15;
  const int quad = lane >> 4;
  const int arow = blockIdx.x * 64 + wave * 16 + l15;
  const unsigned short* xrow = Xb + (size_t)arow * K + quad * 8;

  facc4 acc[NT];
#pragma unroll
  for (int i = 0; i < NT; ++i) acc[i] = (facc4){0.f, 0.f, 0.f, 0.f};

#pragma unroll
  for (int ks = 0; ks < 4; ++ks) {
    bfrag a = *(const bfrag*)(xrow + ks * 32);
#pragma unroll
    for (int ct = 0; ct < NT; ++ct) {
      bfrag b = *(const bfrag*)(&WsT[(ct * 16 + l15) * LSTR + ks * 32 + quad * 8]);
      acc[ct] = __builtin_amdgcn_mfma_f32_16x16x32_bf16(a, b, acc[ct], 0, 0, 0);
    }
  }

  const int orow0 = blockIdx.x * 64 + wave * 16 + quad * 4;
#pragma unroll
  for (int ct = 0; ct < NT; ++ct) {
#pragma unroll
    for (int r = 0; r < 4; ++r) {
      int orow = orow0 + r;
      if (orow < N) H[(size_t)orow * C + ct * 16 + l15] = f2bf(acc[ct][r]);
    }
  }
}

// ---------------------------------------------------------------------------
// Attention scores per node from bf16 H: es = h.a_src, ed = h.a_dst.
// ---------------------------------------------------------------------------
template<int C>
__global__ void escore(const unsigned short* __restrict__ H,
                       const float* __restrict__ a_src,
                       const float* __restrict__ a_dst,
                       float* __restrict__ es, float* __restrict__ ed, int N) {
  const int lane = threadIdx.x & 63;
  const int n = blockIdx.x * (blockDim.x >> 6) + (threadIdx.x >> 6);
  if (n >= N) return;
  float ps, pd;
  if (C == 128) {
    float2 h = bf2x2(((const unsigned*)H)[(size_t)n * 64 + lane]);
    float2 as_ = ((const float2*)a_src)[lane];
    float2 ad_ = ((const float2*)a_dst)[lane];
    ps = h.x * as_.x + h.y * as_.y;
    pd = h.x * ad_.x + h.y * ad_.y;
  } else {
    float h = bf1(H[(size_t)n * C + lane]);
    ps = h * a_src[lane];
    pd = h * a_dst[lane];
  }
  ps = wave_sum(ps);
  pd = wave_sum(pd);
  if (lane == 0) { es[n] = ps; ed[n] = pd; }
}

// ---------------------------------------------------------------------------
// CSR build: histogram -> parallel 3-phase scan -> ranged multi-pass scatter.
// ---------------------------------------------------------------------------
__global__ void csr_count(const int* __restrict__ dst, int* __restrict__ deg, int E) {
  int e = blockIdx.x * blockDim.x + threadIdx.x;
  if (e < E) atomicAdd(deg + dst[e], 1);
}

__global__ void scan_partial(const int* __restrict__ deg, int* __restrict__ csum, int N) {
  __shared__ int sh[256];
  int i = blockIdx.x * 256 + threadIdx.x;
  sh[threadIdx.x] = (i < N) ? deg[i] : 0;
  __syncthreads();
  for (int o = 128; o > 0; o >>= 1) {
    if (threadIdx.x < o) sh[threadIdx.x] += sh[threadIdx.x + o];
    __syncthreads();
  }
  if (threadIdx.x == 0) csum[blockIdx.x] = sh[0];
}

__global__ void scan_chunks(int* __restrict__ csum, int nch) {
  __shared__ int sh[256];
  __shared__ int carry;
  if (threadIdx.x == 0) carry = 0;
  __syncthreads();
  for (int base = 0; base < nch; base += 256) {
    int i = base + threadIdx.x;
    int v = (i < nch) ? csum[i] : 0;
    sh[threadIdx.x] = v;
    __syncthreads();
    for (int o = 1; o < 256; o <<= 1) {
      int t = (threadIdx.x >= o) ? sh[threadIdx.x - o] : 0;
      __syncthreads();
      sh[threadIdx.x] += t;
      __syncthreads();
    }
    if (i < nch) csum[i] = carry + sh[threadIdx.x] - v;
    __syncthreads();
    if (threadIdx.x == 255) carry += sh[255];
    __syncthreads();
  }
}

__global__ void scan_final(const int* __restrict__ deg, const int* __restrict__ csum,
                           int* __restrict__ rp, int* __restrict__ wp, int N, int E) {
  __shared__ int sh[256];
  int i = blockIdx.x * 256 + threadIdx.x;
  int v = (i < N) ? deg[i] : 0;
  sh[threadIdx.x] = v;
  __syncthreads();
  for (int o = 1; o < 256; o <<= 1) {
    int t = (threadIdx.x >= o) ? sh[threadIdx.x - o] : 0;
    __syncthreads();
    sh[threadIdx.x] += t;
    __syncthreads();
  }
  if (i < N) {
    int r = csum[blockIdx.x] + sh[threadIdx.x] - v;
    rp[i] = r;
    wp[i] = r;
  }
  if (blockIdx.x == 0 && threadIdx.x == 0) rp[N] = E;
}

__global__ void csr_scatter_ranged(const int* __restrict__ src,
                                   const int* __restrict__ dst,
                                   int* __restrict__ wp, int* __restrict__ col,
                                   int E, int range, int npass) {
  const int stride = gridDim.x * blockDim.x;
  const int gid = blockIdx.x * blockDim.x + threadIdx.x;
  for (int pass = 0; pass < npass; ++pass) {
    const int lo = pass * range;
    const int hi = lo + range;
    for (int e = gid; e < E; e += stride) {
      int d = dst[e];
      if (d >= lo && d < hi) {
        int p = atomicAdd(wp + d, 1);
        col[p] = src[e];
      }
    }
  }
}

// ---------------------------------------------------------------------------
// Edge softmax per dst node (unchanged).
// ---------------------------------------------------------------------------
__global__ void attn_softmax(const int* __restrict__ row_ptr,
                             const int* __restrict__ col,
                             const float* __restrict__ es,
                             const float* __restrict__ ed,
                             float* __restrict__ alpha,
                             float* __restrict__ den_out,
                             float* __restrict__ selfp_out, int N) {
  const int lane = threadIdx.x & 63;
  const int n = blockIdx.x * (blockDim.x >> 6) + (threadIdx.x >> 6);
  if (n >= N) return;

  const int k0 = row_ptr[n];
  const int k1 = row_ptr[n + 1];
  const int deg = k1 - k0;
  const float edd = ed[n];
  const float self_lg = lrelu(es[n] + edd);

  if (deg <= 64) {
    int k = k0 + lane;
    bool act = (k < k1);
    float lg = act ? lrelu(es[col[k]] + edd) : -3.0e38f;
    float m = fmaxf(wave_max(lg), self_lg);
    float p = act ? __expf(lg - m) : 0.f;
    float den = wave_sum(p);
    float sp = __expf(self_lg - m);
    den += sp;
    if (act) alpha[k] = p;
    if (lane == 0) { den_out[n] = den; selfp_out[n] = sp; }
  } else {
    float m = self_lg;
    for (int base = k0; base < k1; base += 64) {
      int k = base + lane;
      if (k < k1) {
        float lg = lrelu(es[col[k]] + edd);
        alpha[k] = lg;
        m = fmaxf(m, lg);
      }
    }
    m = wave_max(m);
    float den = 0.f;
    for (int base = k0; base < k1; base += 64) {
      int k = base + lane;
      if (k < k1) {
        float p = __expf(alpha[k] - m);
        alpha[k] = p;
        den += p;
      }
    }
    den = wave_sum(den);
    float sp = __expf(self_lg - m);
    den += sp;
    if (lane == 0) { den_out[n] = den; selfp_out[n] = sp; }
  }
}

// ---------------------------------------------------------------------------
// Lean aggregation from bf16 H: one wave/node, 4-edge batches.
// OUT_BF16: write bf16 (next layer's GEMM input) or fp32 (final output).
// ---------------------------------------------------------------------------
template<bool RELU, bool OUT_BF16>
__global__ void gat_gather128(const int* __restrict__ row_ptr,
                              const int* __restrict__ col,
                              const unsigned short* __restrict__ H,
                              const float* __restrict__ alpha,
                              const float* __restrict__ den,
                              const float* __restrict__ selfp,
                              const float* __restrict__ bias,
                              void* __restrict__ outX, int N) {
  const int lane = threadIdx.x & 63;
  const int n = blockIdx.x * (blockDim.x >> 6) + (threadIdx.x >> 6);
  if (n >= N) return;

  const unsigned* Hp = (const unsigned*)H;   // bf16x2 per lane
  float sp = selfp[n];
  float2 hv = bf2x2(Hp[(size_t)n * 64 + lane]);
  float ax0 = sp * hv.x, ay0 = sp * hv.y;
  float ax1 = 0.f, ay1 = 0.f;

  const int k0 = row_ptr[n];
  const int k1 = row_ptr[n + 1];
  int k = k0;
  for (; k + 4 <= k1; k += 4) {
    int s0 = col[k + 0], s1 = col[k + 1], s2 = col[k + 2], s3 = col[k + 3];
    float p0 = alpha[k + 0], p1 = alpha[k + 1], p2 = alpha[k + 2], p3 = alpha[k + 3];
    unsigned u0 = Hp[(size_t)s0 * 64 + lane];
    unsigned u1 = Hp[(size_t)s1 * 64 + lane];
    unsigned u2 = Hp[(size_t)s2 * 64 + lane];
    unsigned u3 = Hp[(size_t)s3 * 64 + lane];
    float2 h0 = bf2x2(u0), h1 = bf2x2(u1), h2 = bf2x2(u2), h3 = bf2x2(u3);
    ax0 += p0 * h0.x; ay0 += p0 * h0.y;
    ax1 += p1 * h1.x; ay1 += p1 * h1.y;
    ax0 += p2 * h2.x; ay0 += p2 * h2.y;
    ax1 += p3 * h3.x; ay1 += p3 * h3.y;
  }
  for (; k < k1; ++k) {
    int s = col[k];
    float p = alpha[k];
    float2 h = bf2x2(Hp[(size_t)s * 64 + lane]);
    ax0 += p * h.x; ay0 += p * h.y;
  }
  float inv = 1.f / den[n];
  float2 bv = ((const float2*)bias)[lane];
  float vx = (ax0 + ax1) * inv + bv.x;
  float vy = (ay0 + ay1) * inv + bv.y;
  if (RELU) { vx = fmaxf(vx, 0.f); vy = fmaxf(vy, 0.f); }
  if (OUT_BF16)
    ((unsigned*)outX)[(size_t)n * 64 + lane] = packbf2(vx, vy);
  else
    ((float2*)outX)[(size_t)n * 64 + lane] = make_float2(vx, vy);
}

template<bool RELU>
__global__ void gat_gather64(const int* __restrict__ row_ptr,
                             const int* __restrict__ col,
                             const unsigned short* __restrict__ H,
                             const float* __restrict__ alpha,
                             const float* __restrict__ den,
                             const float* __restrict__ selfp,
                             const float* __restrict__ bias,
                             float* __restrict__ outX, int N) {
  const int lane = threadIdx.x & 63;
  const int n = blockIdx.x * (blockDim.x >> 6) + (threadIdx.x >> 6);
  if (n >= N) return;

  float a0 = selfp[n] * bf1(H[(size_t)n * 64 + lane]);
  float a1 = 0.f;
  const int k0 = row_ptr[n];
  const int k1 = row_ptr[n + 1];
  int k = k0;
  for (; k + 4 <= k1; k += 4) {
    int s0 = col[k + 0], s1 = col[k + 1], s2 = col[k + 2], s3 = col[k + 3];
    float p0 = alpha[k + 0], p1 = alpha[k + 1], p2 = alpha[k + 2], p3 = alpha[k + 3];
    unsigned short u0 = H[(size_t)s0 * 64 + lane];
    unsigned short u1 = H[(size_t)s1 * 64 + lane];
    unsigned short u2 = H[(size_t)s2 * 64 + lane];
    unsigned short u3 = H[(size_t)s3 * 64 + lane];
    a0 += p0 * bf1(u0); a1 += p1 * bf1(u1);
    a0 += p2 * bf1(u2); a1 += p3 * bf1(u3);
  }
  for (; k < k1; ++k) {
    a0 += alpha[k] * bf1(H[(size_t)col[k] * 64 + lane]);
  }
  float v = (a0 + a1) / den[n] + bias[lane];
  if (RELU) v = fmaxf(v, 0.f);
  outX[(size_t)n * 64 + lane] = v;
}

// ---------------------------------------------------------------------------

extern "C" void kernel_launch(void* const* d_in, const int* in_sizes, int n_in,
                              void* d_out, int out_size, void* d_ws, size_t ws_size,
                              hipStream_t stream) {
  const int C_HID = in_sizes[3];            // 128
  const int C_FIN = in_sizes[11];           // 64
  const int C_IN  = in_sizes[2] / C_HID;    // 128
  const int N     = in_sizes[0] / C_IN;     // 50000
  const int E     = in_sizes[1] / 2;        // 1.6M
  const int NPAD  = ((N + 63) / 64) * 64;   // rows padded to M-tile

  const float* x = (const float*)d_in[0];
  const int* ei  = (const int*)d_in[1];
  const int* src = ei;
  const int* dst = ei + E;

  const float* W0  = (const float*)d_in[2];
  const float* as0 = (const float*)d_in[3];
  const float* ad0 = (const float*)d_in[4];
  const float* b0  = (const float*)d_in[5];
  const float* W1  = (const float*)d_in[6];
  const float* as1 = (const float*)d_in[7];
  const float* ad1 = (const float*)d_in[8];
  const float* b1  = (const float*)d_in[9];
  const float* W2  = (const float*)d_in[10];
  const float* as2 = (const float*)d_in[11];
  const float* ad2 = (const float*)d_in[12];
  const float* b2  = (const float*)d_in[13];

  // Workspace layout (256B aligned)
  char* base = (char*)d_ws;
  size_t off = 0;
  auto alloc = [&](size_t bytes) -> char* {
    char* p = base + off;
    off = (off + bytes + 255) & ~((size_t)255);
    return p;
  };
  const int NCH = (N + 255) / 256;
  unsigned short* XBF = (unsigned short*)alloc((size_t)NPAD * C_HID * 2);  // x in bf16
  unsigned short* XB  = (unsigned short*)alloc((size_t)NPAD * C_HID * 2);  // activations bf16
  unsigned short* H   = (unsigned short*)alloc((size_t)N * C_HID * 2);     // h bf16
  unsigned short* WT  = (unsigned short*)alloc((size_t)C_HID * 128 * 2);   // W^T bf16
  float* ES    = (float*)alloc((size_t)N * sizeof(float));
  float* ED    = (float*)alloc((size_t)N * sizeof(float));
  float* DEN   = (float*)alloc((size_t)N * sizeof(float));
  float* SELFP = (float*)alloc((size_t)N * sizeof(float));
  float* ALPHA = (float*)alloc((size_t)E * sizeof(float));
  int*   RP    = (int*)alloc((size_t)(N + 1) * sizeof(int));
  int*   WP    = (int*)alloc((size_t)N * sizeof(int));
  int*   COL   = (int*)alloc((size_t)E * sizeof(int));
  int*   DEG   = (int*)alloc((size_t)N * sizeof(int));
  int*   CSUM  = (int*)alloc((size_t)NCH * sizeof(int));
  (void)ws_size;

  const int ET256 = (E + 255) / 256;
  const int wgrid = (N + 3) / 4;       // 4 waves (256 thr) per block kernels
  const int mgrid = NPAD / 64;         // mfma gemm: 64 rows per block

  // ---- input conversion + CSR build ----
  conv_x_bf16<<<(NPAD * C_HID + 255) / 256, 256, 0, stream>>>(x, XBF, N * C_HID,
                                                              NPAD * C_HID);
  hipMemsetAsync(DEG, 0, (size_t)N * sizeof(int), stream);
  csr_count<<<ET256, 256, 0, stream>>>(dst, DEG, E);
  scan_partial<<<NCH, 256, 0, stream>>>(DEG, CSUM, N);
  scan_chunks<<<1, 256, 0, stream>>>(CSUM, NCH);
  scan_final<<<NCH, 256, 0, stream>>>(DEG, CSUM, RP, WP, N, E);
  {
    const int NPASS = 8;
    const int range = (N + NPASS - 1) / NPASS;
    csr_scatter_ranged<<<2048, 256, 0, stream>>>(src, dst, WP, COL, E, range, NPASS);
  }

  // ---- Layer 0: XBF -> H -> XB (relu, bf16) ----
  conv_wt<<<(C_HID * 128 + 255) / 256, 256, 0, stream>>>(W0, WT, C_HID);
  gemm_mfma<128><<<mgrid, 256, 0, stream>>>(XBF, WT, H, N);
  escore<128><<<wgrid, 256, 0, stream>>>(H, as0, ad0, ES, ED, N);
  attn_softmax<<<wgrid, 256, 0, stream>>>(RP, COL, ES, ED, ALPHA, DEN, SELFP, N);
  gat_gather128<true, true><<<wgrid, 256, 0, stream>>>(RP, COL, H, ALPHA, DEN, SELFP,
                                                       b0, XB, N);

  // ---- Layer 1: XB -> H -> XB (relu, bf16) ----
  conv_wt<<<(C_HID * 128 + 255) / 256, 256, 0, stream>>>(W1, WT, C_HID);
  gemm_mfma<128><<<mgrid, 256, 0, stream>>>(XB, WT, H, N);
  escore<128><<<wgrid, 256, 0, stream>>>(H, as1, ad1, ES, ED, N);
  attn_softmax<<<wgrid, 256, 0, stream>>>(RP, COL, ES, ED, ALPHA, DEN, SELFP, N);
  gat_gather128<true, true><<<wgrid, 256, 0, stream>>>(RP, COL, H, ALPHA, DEN, SELFP,
                                                       b1, XB, N);

  // ---- Layer 2: XB -> H -> d_out (no relu, fp32) ----
  conv_wt<<<(C_FIN * 128 + 255) / 256, 256, 0, stream>>>(W2, WT, C_FIN);
  gemm_mfma<64><<<mgrid, 256, 0, stream>>>(XB, WT, H, N);
  escore<64><<<wgrid, 256, 0, stream>>>(H, as2, ad2, ES, ED, N);
  attn_softmax<<<wgrid, 256, 0, stream>>>(RP, COL, ES, ED, ALPHA, DEN, SELFP, N);
  gat_gather64<false><<<wgrid, 256, 0, stream>>>(RP, COL, H, ALPHA, DEN, SELFP, b2,
                                                 (float*)d_out, N);
  (void)out_size; (void)n_in;
}

// Round 11
// 461.526 us; speedup vs baseline: 4.0437x; 1.2015x over previous
//
#include <hip/hip_runtime.h>
#include <hip/hip_bf16.h>

#define DEVFN __device__ __forceinline__

typedef __attribute__((ext_vector_type(8))) short bfrag;   // 8 bf16 (4 VGPRs)
typedef __attribute__((ext_vector_type(4))) float facc4;   // 4 fp32 acc

DEVFN float lrelu(float v) { return (v >= 0.f) ? v : 0.2f * v; }

// packed bf16x2 (uint) -> 2 floats; elem0 = low 16 bits
DEVFN float2 bf2x2(unsigned u) {
  return make_float2(__uint_as_float(u << 16), __uint_as_float(u & 0xFFFF0000u));
}
DEVFN float bf1(unsigned short b) { return __uint_as_float(((unsigned)b) << 16); }
DEVFN unsigned short f2bf(float f) {
  __hip_bfloat16 h = __float2bfloat16(f);
  return *reinterpret_cast<unsigned short*>(&h);
}
DEVFN unsigned packbf2(float x, float y) {
  return (unsigned)f2bf(x) | ((unsigned)f2bf(y) << 16);
}

DEVFN float wave_sum(float v) {
#pragma unroll
  for (int o = 1; o < 64; o <<= 1) v += __shfl_xor(v, o, 64);
  return v;
}
DEVFN float wave_max(float v) {
#pragma unroll
  for (int o = 1; o < 64; o <<= 1) v = fmaxf(v, __shfl_xor(v, o, 64));
  return v;
}

// ---------------------------------------------------------------------------
// fp32 -> bf16 conversions (X once; W transposed per layer).
// ---------------------------------------------------------------------------
__global__ void conv_x_bf16(const float* __restrict__ in,
                            unsigned short* __restrict__ out,
                            int n_valid, int n_total) {
  int i = blockIdx.x * 256 + threadIdx.x;
  if (i < n_total) out[i] = f2bf(i < n_valid ? in[i] : 0.f);
}

// WT[c][k] = bf16(W[k][c]);  K=128 fixed.
__global__ void conv_wt(const float* __restrict__ W, unsigned short* __restrict__ WT,
                        int Cc) {
  int i = blockIdx.x * 256 + threadIdx.x;
  if (i < Cc * 128) {
    int k = i & 127;
    int c = i >> 7;
    WT[i] = f2bf(W[k * Cc + c]);
  }
}

// ---------------------------------------------------------------------------
// MFMA GEMM + fused escore: H[N][C] = X[N][128] @ W[128][C] (bf16 in/out,
// fp32 acc); es/ed computed from fp32 accumulators in the epilogue.
// Block: 64 rows x C cols, 4 waves. mfma_f32_16x16x32_bf16 layouts (m89):
// A[m=lane&15][k=quad*8+j], B[k][n=lane&15], D[row=quad*4+reg][col=lane&15].
// ---------------------------------------------------------------------------
template<int C>
__global__ __launch_bounds__(256) void gemm_mfma(const unsigned short* __restrict__ Xb,
                                                 const unsigned short* __restrict__ WT,
                                                 const float* __restrict__ a_src,
                                                 const float* __restrict__ a_dst,
                                                 unsigned short* __restrict__ H,
                                                 float* __restrict__ es,
                                                 float* __restrict__ ed,
                                                 int N) {
  constexpr int K = 128;
  constexpr int LSTR = K + 8;          // halfword stride, breaks bank alignment
  constexpr int NT = C / 16;           // col tiles
  __shared__ unsigned short WsT[C * LSTR];

  const int t = threadIdx.x;
  // stage WT (C x 128 bf16) -> LDS with padded stride; 16B per thread-iter
  {
    const int r0 = t >> 4;             // 16 rows per sweep
    const int o = (t & 15) * 8;
    for (int r = r0; r < C; r += 16) {
      *(float4*)(&WsT[r * LSTR + o]) = *(const float4*)(WT + r * K + o);
    }
  }
  __syncthreads();

  const int wave = t >> 6;
  const int lane = t & 63;
  const int l15 = lane & 15;
  const int quad = lane >> 4;
  const int arow = blockIdx.x * 64 + wave * 16 + l15;
  const unsigned short* xrow = Xb + (size_t)arow * K + quad * 8;

  facc4 acc[NT];
#pragma unroll
  for (int i = 0; i < NT; ++i) acc[i] = (facc4){0.f, 0.f, 0.f, 0.f};

#pragma unroll
  for (int ks = 0; ks < 4; ++ks) {
    bfrag a = *(const bfrag*)(xrow + ks * 32);
#pragma unroll
    for (int ct = 0; ct < NT; ++ct) {
      bfrag b = *(const bfrag*)(&WsT[(ct * 16 + l15) * LSTR + ks * 32 + quad * 8]);
      acc[ct] = __builtin_amdgcn_mfma_f32_16x16x32_bf16(a, b, acc[ct], 0, 0, 0);
    }
  }

  // attention vectors for fused escore
  float asv[NT], adv[NT];
#pragma unroll
  for (int ct = 0; ct < NT; ++ct) {
    asv[ct] = a_src[ct * 16 + l15];
    adv[ct] = a_dst[ct * 16 + l15];
  }

  const int orow0 = blockIdx.x * 64 + wave * 16 + quad * 4;
#pragma unroll
  for (int r = 0; r < 4; ++r) {
    const int orow = orow0 + r;
    float ps = 0.f, pd = 0.f;
#pragma unroll
    for (int ct = 0; ct < NT; ++ct) {
      if (orow < N) H[(size_t)orow * C + ct * 16 + l15] = f2bf(acc[ct][r]);
      ps += acc[ct][r] * asv[ct];
      pd += acc[ct][r] * adv[ct];
    }
    // reduce across the 16 lanes of this quad
#pragma unroll
    for (int msk = 1; msk < 16; msk <<= 1) {
      ps += __shfl_xor(ps, msk, 64);
      pd += __shfl_xor(pd, msk, 64);
    }
    if (l15 == 0 && orow < N) { es[orow] = ps; ed[orow] = pd; }
  }
}

// ---------------------------------------------------------------------------
// CSR build: histogram -> parallel 3-phase scan -> ranged multi-pass scatter.
// ---------------------------------------------------------------------------
__global__ void csr_count(const int* __restrict__ dst, int* __restrict__ deg, int E) {
  int e = blockIdx.x * blockDim.x + threadIdx.x;
  if (e < E) atomicAdd(deg + dst[e], 1);
}

__global__ void scan_partial(const int* __restrict__ deg, int* __restrict__ csum, int N) {
  __shared__ int sh[256];
  int i = blockIdx.x * 256 + threadIdx.x;
  sh[threadIdx.x] = (i < N) ? deg[i] : 0;
  __syncthreads();
  for (int o = 128; o > 0; o >>= 1) {
    if (threadIdx.x < o) sh[threadIdx.x] += sh[threadIdx.x + o];
    __syncthreads();
  }
  if (threadIdx.x == 0) csum[blockIdx.x] = sh[0];
}

__global__ void scan_chunks(int* __restrict__ csum, int nch) {
  __shared__ int sh[256];
  __shared__ int carry;
  if (threadIdx.x == 0) carry = 0;
  __syncthreads();
  for (int base = 0; base < nch; base += 256) {
    int i = base + threadIdx.x;
    int v = (i < nch) ? csum[i] : 0;
    sh[threadIdx.x] = v;
    __syncthreads();
    for (int o = 1; o < 256; o <<= 1) {
      int t = (threadIdx.x >= o) ? sh[threadIdx.x - o] : 0;
      __syncthreads();
      sh[threadIdx.x] += t;
      __syncthreads();
    }
    if (i < nch) csum[i] = carry + sh[threadIdx.x] - v;
    __syncthreads();
    if (threadIdx.x == 255) carry += sh[255];
    __syncthreads();
  }
}

__global__ void scan_final(const int* __restrict__ deg, const int* __restrict__ csum,
                           int* __restrict__ rp, int* __restrict__ wp, int N, int E) {
  __shared__ int sh[256];
  int i = blockIdx.x * 256 + threadIdx.x;
  int v = (i < N) ? deg[i] : 0;
  sh[threadIdx.x] = v;
  __syncthreads();
  for (int o = 1; o < 256; o <<= 1) {
    int t = (threadIdx.x >= o) ? sh[threadIdx.x - o] : 0;
    __syncthreads();
    sh[threadIdx.x] += t;
    __syncthreads();
  }
  if (i < N) {
    int r = csum[blockIdx.x] + sh[threadIdx.x] - v;
    rp[i] = r;
    wp[i] = r;
  }
  if (blockIdx.x == 0 && threadIdx.x == 0) rp[N] = E;
}

__global__ void csr_scatter_ranged(const int* __restrict__ src,
                                   const int* __restrict__ dst,
                                   int* __restrict__ wp, int* __restrict__ col,
                                   int E, int range, int npass) {
  const int stride = gridDim.x * blockDim.x;
  const int gid = blockIdx.x * blockDim.x + threadIdx.x;
  for (int pass = 0; pass < npass; ++pass) {
    const int lo = pass * range;
    const int hi = lo + range;
    for (int e = gid; e < E; e += stride) {
      int d = dst[e];
      if (d >= lo && d < hi) {
        int p = atomicAdd(wp + d, 1);
        col[p] = src[e];
      }
    }
  }
}

// ---------------------------------------------------------------------------
// Fully fused GAT edge stage: softmax (register phase, lanes=edges) +
// gather (lanes=channels) with (col,p) broadcast via __shfl. No LDS, no
// barriers, no alpha round-trip. One wave per dst node.
// ---------------------------------------------------------------------------
template<bool RELU, bool OUT_BF16>
__global__ void gat_fused128(const int* __restrict__ row_ptr,
                             const int* __restrict__ col,
                             const float* __restrict__ es,
                             const float* __restrict__ ed,
                             const unsigned short* __restrict__ H,
                             const float* __restrict__ bias,
                             void* __restrict__ outX, int N) {
  const int lane = threadIdx.x & 63;
  const int n = blockIdx.x * (blockDim.x >> 6) + (threadIdx.x >> 6);
  if (n >= N) return;

  const int k0 = row_ptr[n];
  const int k1 = row_ptr[n + 1];
  const int deg = k1 - k0;
  const float edd = ed[n];
  const float self_lg = lrelu(es[n] + edd);

  const unsigned* Hp = (const unsigned*)H;   // bf16x2 per lane
  float ax0 = 0.f, ay0 = 0.f, ax1 = 0.f, ay1 = 0.f;
  float den, sp;

  if (deg <= 64) {
    // phase A (lanes = edges): logits, max, exp, denom — all in registers
    int k = k0 + lane;
    bool act = (k < k1);
    int c = act ? col[k] : 0;
    float lg = act ? lrelu(es[c] + edd) : -3.0e38f;
    float m = fmaxf(wave_max(lg), self_lg);
    float p = act ? __expf(lg - m) : 0.f;
    sp = __expf(self_lg - m);
    den = wave_sum(p) + sp;
    // phase B (lanes = channels): broadcast (c,p) of edge j from lane j
    int j = 0;
    for (; j + 4 <= deg; j += 4) {
      int s0 = __shfl(c, j), s1 = __shfl(c, j + 1);
      int s2 = __shfl(c, j + 2), s3 = __shfl(c, j + 3);
      float p0 = __shfl(p, j), p1 = __shfl(p, j + 1);
      float p2 = __shfl(p, j + 2), p3 = __shfl(p, j + 3);
      unsigned u0 = Hp[(size_t)s0 * 64 + lane];
      unsigned u1 = Hp[(size_t)s1 * 64 + lane];
      unsigned u2 = Hp[(size_t)s2 * 64 + lane];
      unsigned u3 = Hp[(size_t)s3 * 64 + lane];
      float2 h0 = bf2x2(u0), h1 = bf2x2(u1), h2 = bf2x2(u2), h3 = bf2x2(u3);
      ax0 += p0 * h0.x; ay0 += p0 * h0.y;
      ax1 += p1 * h1.x; ay1 += p1 * h1.y;
      ax0 += p2 * h2.x; ay0 += p2 * h2.y;
      ax1 += p3 * h3.x; ay1 += p3 * h3.y;
    }
    for (; j < deg; ++j) {
      int s = __shfl(c, j);
      float pj = __shfl(p, j);
      float2 h = bf2x2(Hp[(size_t)s * 64 + lane]);
      ax0 += pj * h.x; ay0 += pj * h.y;
    }
  } else {
    // general path (rare): pass 1 = max, pass 2 = exp + chunked gather
    float mloc = self_lg;
    for (int base = k0; base < k1; base += 64) {
      int k = base + lane;
      if (k < k1) mloc = fmaxf(mloc, lrelu(es[col[k]] + edd));
    }
    float m = wave_max(mloc);
    sp = __expf(self_lg - m);
    den = sp;
    for (int base = k0; base < k1; base += 64) {
      int k = base + lane;
      bool act = (k < k1);
      int c = act ? col[k] : 0;
      float p = act ? __expf(lrelu(es[c] + edd) - m) : 0.f;
      den += wave_sum(p);
      int len = min(64, k1 - base);
      for (int j = 0; j < len; ++j) {
        int s = __shfl(c, j);
        float pj = __shfl(p, j);
        float2 h = bf2x2(Hp[(size_t)s * 64 + lane]);
        ax0 += pj * h.x; ay0 += pj * h.y;
      }
    }
  }

  // self contribution + epilogue
  float2 hv = bf2x2(Hp[(size_t)n * 64 + lane]);
  ax0 += sp * hv.x; ay0 += sp * hv.y;
  float inv = 1.f / den;
  float2 bv = ((const float2*)bias)[lane];
  float vx = (ax0 + ax1) * inv + bv.x;
  float vy = (ay0 + ay1) * inv + bv.y;
  if (RELU) { vx = fmaxf(vx, 0.f); vy = fmaxf(vy, 0.f); }
  if (OUT_BF16)
    ((unsigned*)outX)[(size_t)n * 64 + lane] = packbf2(vx, vy);
  else
    ((float2*)outX)[(size_t)n * 64 + lane] = make_float2(vx, vy);
}

template<bool RELU>
__global__ void gat_fused64(const int* __restrict__ row_ptr,
                            const int* __restrict__ col,
                            const float* __restrict__ es,
                            const float* __restrict__ ed,
                            const unsigned short* __restrict__ H,
                            const float* __restrict__ bias,
                            float* __restrict__ outX, int N) {
  const int lane = threadIdx.x & 63;
  const int n = blockIdx.x * (blockDim.x >> 6) + (threadIdx.x >> 6);
  if (n >= N) return;

  const int k0 = row_ptr[n];
  const int k1 = row_ptr[n + 1];
  const int deg = k1 - k0;
  const float edd = ed[n];
  const float self_lg = lrelu(es[n] + edd);

  float a0 = 0.f, a1 = 0.f;
  float den, sp;

  if (deg <= 64) {
    int k = k0 + lane;
    bool act = (k < k1);
    int c = act ? col[k] : 0;
    float lg = act ? lrelu(es[c] + edd) : -3.0e38f;
    float m = fmaxf(wave_max(lg), self_lg);
    float p = act ? __expf(lg - m) : 0.f;
    sp = __expf(self_lg - m);
    den = wave_sum(p) + sp;
    int j = 0;
    for (; j + 4 <= deg; j += 4) {
      int s0 = __shfl(c, j), s1 = __shfl(c, j + 1);
      int s2 = __shfl(c, j + 2), s3 = __shfl(c, j + 3);
      float p0 = __shfl(p, j), p1 = __shfl(p, j + 1);
      float p2 = __shfl(p, j + 2), p3 = __shfl(p, j + 3);
      unsigned short u0 = H[(size_t)s0 * 64 + lane];
      unsigned short u1 = H[(size_t)s1 * 64 + lane];
      unsigned short u2 = H[(size_t)s2 * 64 + lane];
      unsigned short u3 = H[(size_t)s3 * 64 + lane];
      a0 += p0 * bf1(u0); a1 += p1 * bf1(u1);
      a0 += p2 * bf1(u2); a1 += p3 * bf1(u3);
    }
    for (; j < deg; ++j) {
      int s = __shfl(c, j);
      float pj = __shfl(p, j);
      a0 += pj * bf1(H[(size_t)s * 64 + lane]);
    }
  } else {
    float mloc = self_lg;
    for (int base = k0; base < k1; base += 64) {
      int k = base + lane;
      if (k < k1) mloc = fmaxf(mloc, lrelu(es[col[k]] + edd));
    }
    float m = wave_max(mloc);
    sp = __expf(self_lg - m);
    den = sp;
    for (int base = k0; base < k1; base += 64) {
      int k = base + lane;
      bool act = (k < k1);
      int c = act ? col[k] : 0;
      float p = act ? __expf(lrelu(es[c] + edd) - m) : 0.f;
      den += wave_sum(p);
      int len = min(64, k1 - base);
      for (int j = 0; j < len; ++j) {
        int s = __shfl(c, j);
        float pj = __shfl(p, j);
        a0 += pj * bf1(H[(size_t)s * 64 + lane]);
      }
    }
  }

  a0 += sp * bf1(H[(size_t)n * 64 + lane]);
  float v = (a0 + a1) / den + bias[lane];
  if (RELU) v = fmaxf(v, 0.f);
  outX[(size_t)n * 64 + lane] = v;
}

// ---------------------------------------------------------------------------

extern "C" void kernel_launch(void* const* d_in, const int* in_sizes, int n_in,
                              void* d_out, int out_size, void* d_ws, size_t ws_size,
                              hipStream_t stream) {
  const int C_HID = in_sizes[3];            // 128
  const int C_FIN = in_sizes[11];           // 64
  const int C_IN  = in_sizes[2] / C_HID;    // 128
  const int N     = in_sizes[0] / C_IN;     // 50000
  const int E     = in_sizes[1] / 2;        // 1.6M
  const int NPAD  = ((N + 63) / 64) * 64;   // rows padded to M-tile

  const float* x = (const float*)d_in[0];
  const int* ei  = (const int*)d_in[1];
  const int* src = ei;
  const int* dst = ei + E;

  const float* W0  = (const float*)d_in[2];
  const float* as0 = (const float*)d_in[3];
  const float* ad0 = (const float*)d_in[4];
  const float* b0  = (const float*)d_in[5];
  const float* W1  = (const float*)d_in[6];
  const float* as1 = (const float*)d_in[7];
  const float* ad1 = (const float*)d_in[8];
  const float* b1  = (const float*)d_in[9];
  const float* W2  = (const float*)d_in[10];
  const float* as2 = (const float*)d_in[11];
  const float* ad2 = (const float*)d_in[12];
  const float* b2  = (const float*)d_in[13];

  // Workspace layout (256B aligned)
  char* base = (char*)d_ws;
  size_t off = 0;
  auto alloc = [&](size_t bytes) -> char* {
    char* p = base + off;
    off = (off + bytes + 255) & ~((size_t)255);
    return p;
  };
  const int NCH = (N + 255) / 256;
  unsigned short* XBF = (unsigned short*)alloc((size_t)NPAD * C_HID * 2);  // x bf16
  unsigned short* XB  = (unsigned short*)alloc((size_t)NPAD * C_HID * 2);  // acts bf16
  unsigned short* H   = (unsigned short*)alloc((size_t)N * C_HID * 2);     // h bf16
  unsigned short* WT  = (unsigned short*)alloc((size_t)C_HID * 128 * 2);   // W^T bf16
  float* ES    = (float*)alloc((size_t)N * sizeof(float));
  float* ED    = (float*)alloc((size_t)N * sizeof(float));
  int*   RP    = (int*)alloc((size_t)(N + 1) * sizeof(int));
  int*   WP    = (int*)alloc((size_t)N * sizeof(int));
  int*   COL   = (int*)alloc((size_t)E * sizeof(int));
  int*   DEG   = (int*)alloc((size_t)N * sizeof(int));
  int*   CSUM  = (int*)alloc((size_t)NCH * sizeof(int));
  (void)ws_size;

  const int ET256 = (E + 255) / 256;
  const int wgrid = (N + 3) / 4;       // 4 waves (256 thr) per block kernels
  const int mgrid = NPAD / 64;         // mfma gemm: 64 rows per block

  // ---- input conversion + CSR build ----
  conv_x_bf16<<<(NPAD * C_HID + 255) / 256, 256, 0, stream>>>(x, XBF, N * C_HID,
                                                              NPAD * C_HID);
  hipMemsetAsync(DEG, 0, (size_t)N * sizeof(int), stream);
  csr_count<<<ET256, 256, 0, stream>>>(dst, DEG, E);
  scan_partial<<<NCH, 256, 0, stream>>>(DEG, CSUM, N);
  scan_chunks<<<1, 256, 0, stream>>>(CSUM, NCH);
  scan_final<<<NCH, 256, 0, stream>>>(DEG, CSUM, RP, WP, N, E);
  {
    const int NPASS = 8;
    const int range = (N + NPASS - 1) / NPASS;
    csr_scatter_ranged<<<2048, 256, 0, stream>>>(src, dst, WP, COL, E, range, NPASS);
  }

  // ---- Layer 0: XBF -> H(+es/ed) -> XB (relu, bf16) ----
  conv_wt<<<(C_HID * 128 + 255) / 256, 256, 0, stream>>>(W0, WT, C_HID);
  gemm_mfma<128><<<mgrid, 256, 0, stream>>>(XBF, WT, as0, ad0, H, ES, ED, N);
  gat_fused128<true, true><<<wgrid, 256, 0, stream>>>(RP, COL, ES, ED, H, b0, XB, N);

  // ---- Layer 1: XB -> H(+es/ed) -> XB (relu, bf16) ----
  conv_wt<<<(C_HID * 128 + 255) / 256, 256, 0, stream>>>(W1, WT, C_HID);
  gemm_mfma<128><<<mgrid, 256, 0, stream>>>(XB, WT, as1, ad1, H, ES, ED, N);
  gat_fused128<true, true><<<wgrid, 256, 0, stream>>>(RP, COL, ES, ED, H, b1, XB, N);

  // ---- Layer 2: XB -> H(+es/ed) -> d_out (no relu, fp32) ----
  conv_wt<<<(C_FIN * 128 + 255) / 256, 256, 0, stream>>>(W2, WT, C_FIN);
  gemm_mfma<64><<<mgrid, 256, 0, stream>>>(XB, WT, as2, ad2, H, ES, ED, N);
  gat_fused64<false><<<wgrid, 256, 0, stream>>>(RP, COL, ES, ED, H, b2,
                                                (float*)d_out, N);
  (void)out_size; (void)n_in;
}

// Round 12
// 459.608 us; speedup vs baseline: 4.0606x; 1.0042x over previous
//
#include <hip/hip_runtime.h>
#include <hip/hip_bf16.h>

#define DEVFN __device__ __forceinline__

typedef __attribute__((ext_vector_type(8))) short bfrag;   // 8 bf16 (4 VGPRs)
typedef __attribute__((ext_vector_type(4))) float facc4;   // 4 fp32 acc

DEVFN float lrelu(float v) { return (v >= 0.f) ? v : 0.2f * v; }

// packed bf16x2 (uint) -> 2 floats; elem0 = low 16 bits
DEVFN float2 bf2x2(unsigned u) {
  return make_float2(__uint_as_float(u << 16), __uint_as_float(u & 0xFFFF0000u));
}
DEVFN float bf1(unsigned short b) { return __uint_as_float(((unsigned)b) << 16); }
DEVFN unsigned short f2bf(float f) {
  __hip_bfloat16 h = __float2bfloat16(f);
  return *reinterpret_cast<unsigned short*>(&h);
}
DEVFN unsigned packbf2(float x, float y) {
  return (unsigned)f2bf(x) | ((unsigned)f2bf(y) << 16);
}

DEVFN float wave_sum(float v) {
#pragma unroll
  for (int o = 1; o < 64; o <<= 1) v += __shfl_xor(v, o, 64);
  return v;
}
DEVFN float wave_max(float v) {
#pragma unroll
  for (int o = 1; o < 64; o <<= 1) v = fmaxf(v, __shfl_xor(v, o, 64));
  return v;
}

// ---------------------------------------------------------------------------
// fp32 -> bf16 conversions (X once; W transposed per layer).
// ---------------------------------------------------------------------------
__global__ void conv_x_bf16(const float* __restrict__ in,
                            unsigned short* __restrict__ out,
                            int n_valid, int n_total) {
  int i = blockIdx.x * 256 + threadIdx.x;
  if (i < n_total) out[i] = f2bf(i < n_valid ? in[i] : 0.f);
}

// WT[c][k] = bf16(W[k][c]);  K=128 fixed.
__global__ void conv_wt(const float* __restrict__ W, unsigned short* __restrict__ WT,
                        int Cc) {
  int i = blockIdx.x * 256 + threadIdx.x;
  if (i < Cc * 128) {
    int k = i & 127;
    int c = i >> 7;
    WT[i] = f2bf(W[k * Cc + c]);
  }
}

// ---------------------------------------------------------------------------
// MFMA GEMM + fused escore (unchanged from r11).
// ---------------------------------------------------------------------------
template<int C>
__global__ __launch_bounds__(256) void gemm_mfma(const unsigned short* __restrict__ Xb,
                                                 const unsigned short* __restrict__ WT,
                                                 const float* __restrict__ a_src,
                                                 const float* __restrict__ a_dst,
                                                 unsigned short* __restrict__ H,
                                                 float* __restrict__ es,
                                                 float* __restrict__ ed,
                                                 int N) {
  constexpr int K = 128;
  constexpr int LSTR = K + 8;
  constexpr int NT = C / 16;
  __shared__ unsigned short WsT[C * LSTR];

  const int t = threadIdx.x;
  {
    const int r0 = t >> 4;
    const int o = (t & 15) * 8;
    for (int r = r0; r < C; r += 16) {
      *(float4*)(&WsT[r * LSTR + o]) = *(const float4*)(WT + r * K + o);
    }
  }
  __syncthreads();

  const int wave = t >> 6;
  const int lane = t & 63;
  const int l15 = lane & 15;
  const int quad = lane >> 4;
  const int arow = blockIdx.x * 64 + wave * 16 + l15;
  const unsigned short* xrow = Xb + (size_t)arow * K + quad * 8;

  facc4 acc[NT];
#pragma unroll
  for (int i = 0; i < NT; ++i) acc[i] = (facc4){0.f, 0.f, 0.f, 0.f};

#pragma unroll
  for (int ks = 0; ks < 4; ++ks) {
    bfrag a = *(const bfrag*)(xrow + ks * 32);
#pragma unroll
    for (int ct = 0; ct < NT; ++ct) {
      bfrag b = *(const bfrag*)(&WsT[(ct * 16 + l15) * LSTR + ks * 32 + quad * 8]);
      acc[ct] = __builtin_amdgcn_mfma_f32_16x16x32_bf16(a, b, acc[ct], 0, 0, 0);
    }
  }

  float asv[NT], adv[NT];
#pragma unroll
  for (int ct = 0; ct < NT; ++ct) {
    asv[ct] = a_src[ct * 16 + l15];
    adv[ct] = a_dst[ct * 16 + l15];
  }

  const int orow0 = blockIdx.x * 64 + wave * 16 + quad * 4;
#pragma unroll
  for (int r = 0; r < 4; ++r) {
    const int orow = orow0 + r;
    float ps = 0.f, pd = 0.f;
#pragma unroll
    for (int ct = 0; ct < NT; ++ct) {
      if (orow < N) H[(size_t)orow * C + ct * 16 + l15] = f2bf(acc[ct][r]);
      ps += acc[ct][r] * asv[ct];
      pd += acc[ct][r] * adv[ct];
    }
#pragma unroll
    for (int msk = 1; msk < 16; msk <<= 1) {
      ps += __shfl_xor(ps, msk, 64);
      pd += __shfl_xor(pd, msk, 64);
    }
    if (l15 == 0 && orow < N) { es[orow] = ps; ed[orow] = pd; }
  }
}

// ---------------------------------------------------------------------------
// CSR build: histogram -> parallel 3-phase scan -> ranged multi-pass scatter.
// ---------------------------------------------------------------------------
__global__ void csr_count(const int* __restrict__ dst, int* __restrict__ deg, int E) {
  int e = blockIdx.x * blockDim.x + threadIdx.x;
  if (e < E) atomicAdd(deg + dst[e], 1);
}

__global__ void scan_partial(const int* __restrict__ deg, int* __restrict__ csum, int N) {
  __shared__ int sh[256];
  int i = blockIdx.x * 256 + threadIdx.x;
  sh[threadIdx.x] = (i < N) ? deg[i] : 0;
  __syncthreads();
  for (int o = 128; o > 0; o >>= 1) {
    if (threadIdx.x < o) sh[threadIdx.x] += sh[threadIdx.x + o];
    __syncthreads();
  }
  if (threadIdx.x == 0) csum[blockIdx.x] = sh[0];
}

__global__ void scan_chunks(int* __restrict__ csum, int nch) {
  __shared__ int sh[256];
  __shared__ int carry;
  if (threadIdx.x == 0) carry = 0;
  __syncthreads();
  for (int base = 0; base < nch; base += 256) {
    int i = base + threadIdx.x;
    int v = (i < nch) ? csum[i] : 0;
    sh[threadIdx.x] = v;
    __syncthreads();
    for (int o = 1; o < 256; o <<= 1) {
      int t = (threadIdx.x >= o) ? sh[threadIdx.x - o] : 0;
      __syncthreads();
      sh[threadIdx.x] += t;
      __syncthreads();
    }
    if (i < nch) csum[i] = carry + sh[threadIdx.x] - v;
    __syncthreads();
    if (threadIdx.x == 255) carry += sh[255];
    __syncthreads();
  }
}

__global__ void scan_final(const int* __restrict__ deg, const int* __restrict__ csum,
                           int* __restrict__ rp, int* __restrict__ wp, int N, int E) {
  __shared__ int sh[256];
  int i = blockIdx.x * 256 + threadIdx.x;
  int v = (i < N) ? deg[i] : 0;
  sh[threadIdx.x] = v;
  __syncthreads();
  for (int o = 1; o < 256; o <<= 1) {
    int t = (threadIdx.x >= o) ? sh[threadIdx.x - o] : 0;
    __syncthreads();
    sh[threadIdx.x] += t;
    __syncthreads();
  }
  if (i < N) {
    int r = csum[blockIdx.x] + sh[threadIdx.x] - v;
    rp[i] = r;
    wp[i] = r;
  }
  if (blockIdx.x == 0 && threadIdx.x == 0) rp[N] = E;
}

// Ranged multi-pass scatter; IT = uint16 when N < 65536 (halves write bytes).
template<typename IT>
__global__ void csr_scatter_ranged(const int* __restrict__ src,
                                   const int* __restrict__ dst,
                                   int* __restrict__ wp, IT* __restrict__ col,
                                   int E, int range, int npass) {
  const int stride = gridDim.x * blockDim.x;
  const int gid = blockIdx.x * blockDim.x + threadIdx.x;
  for (int pass = 0; pass < npass; ++pass) {
    const int lo = pass * range;
    const int hi = lo + range;
    for (int e = gid; e < E; e += stride) {
      int d = dst[e];
      if (d >= lo && d < hi) {
        int p = atomicAdd(wp + d, 1);
        col[p] = (IT)src[e];
      }
    }
  }
}

// ---------------------------------------------------------------------------
// Fully fused GAT edge stage (softmax in registers + gather via __shfl
// broadcast). 8-edge batches -> 8 independent H loads in flight per wave.
// ---------------------------------------------------------------------------
template<bool RELU, bool OUT_BF16, typename IT>
__global__ void gat_fused128(const int* __restrict__ row_ptr,
                             const IT* __restrict__ col,
                             const float* __restrict__ es,
                             const float* __restrict__ ed,
                             const unsigned short* __restrict__ H,
                             const float* __restrict__ bias,
                             void* __restrict__ outX, int N) {
  const int lane = threadIdx.x & 63;
  const int n = blockIdx.x * (blockDim.x >> 6) + (threadIdx.x >> 6);
  if (n >= N) return;

  const int k0 = row_ptr[n];
  const int k1 = row_ptr[n + 1];
  const int deg = k1 - k0;
  const float edd = ed[n];
  const float self_lg = lrelu(es[n] + edd);

  const unsigned* Hp = (const unsigned*)H;   // bf16x2 per lane
  float ax0 = 0.f, ay0 = 0.f, ax1 = 0.f, ay1 = 0.f;
  float den, sp;

  if (deg <= 64) {
    // phase A (lanes = edges)
    int k = k0 + lane;
    bool act = (k < k1);
    int c = act ? (int)col[k] : 0;
    float lg = act ? lrelu(es[c] + edd) : -3.0e38f;
    float m = fmaxf(wave_max(lg), self_lg);
    float p = act ? __expf(lg - m) : 0.f;
    sp = __expf(self_lg - m);
    den = wave_sum(p) + sp;
    // phase B (lanes = channels): 8-edge batches
    int j = 0;
    for (; j + 8 <= deg; j += 8) {
      int ss[8];
      float pp[8];
      unsigned uu[8];
#pragma unroll
      for (int q = 0; q < 8; ++q) {
        ss[q] = __shfl(c, j + q);
        pp[q] = __shfl(p, j + q);
      }
#pragma unroll
      for (int q = 0; q < 8; ++q) uu[q] = Hp[(size_t)ss[q] * 64 + lane];
#pragma unroll
      for (int q = 0; q < 8; ++q) {
        float2 h = bf2x2(uu[q]);
        if (q & 1) { ax1 += pp[q] * h.x; ay1 += pp[q] * h.y; }
        else       { ax0 += pp[q] * h.x; ay0 += pp[q] * h.y; }
      }
    }
    for (; j < deg; ++j) {
      int s = __shfl(c, j);
      float pj = __shfl(p, j);
      float2 h = bf2x2(Hp[(size_t)s * 64 + lane]);
      ax0 += pj * h.x; ay0 += pj * h.y;
    }
  } else {
    // general path (rare): pass 1 = max, pass 2 = exp + chunked gather
    float mloc = self_lg;
    for (int base = k0; base < k1; base += 64) {
      int k = base + lane;
      if (k < k1) mloc = fmaxf(mloc, lrelu(es[(int)col[k]] + edd));
    }
    float m = wave_max(mloc);
    sp = __expf(self_lg - m);
    den = sp;
    for (int base = k0; base < k1; base += 64) {
      int k = base + lane;
      bool act = (k < k1);
      int c = act ? (int)col[k] : 0;
      float p = act ? __expf(lrelu(es[c] + edd) - m) : 0.f;
      den += wave_sum(p);
      int len = min(64, k1 - base);
      for (int j = 0; j < len; ++j) {
        int s = __shfl(c, j);
        float pj = __shfl(p, j);
        float2 h = bf2x2(Hp[(size_t)s * 64 + lane]);
        ax0 += pj * h.x; ay0 += pj * h.y;
      }
    }
  }

  float2 hv = bf2x2(Hp[(size_t)n * 64 + lane]);
  ax0 += sp * hv.x; ay0 += sp * hv.y;
  float inv = 1.f / den;
  float2 bv = ((const float2*)bias)[lane];
  float vx = (ax0 + ax1) * inv + bv.x;
  float vy = (ay0 + ay1) * inv + bv.y;
  if (RELU) { vx = fmaxf(vx, 0.f); vy = fmaxf(vy, 0.f); }
  if (OUT_BF16)
    ((unsigned*)outX)[(size_t)n * 64 + lane] = packbf2(vx, vy);
  else
    ((float2*)outX)[(size_t)n * 64 + lane] = make_float2(vx, vy);
}

template<bool RELU, typename IT>
__global__ void gat_fused64(const int* __restrict__ row_ptr,
                            const IT* __restrict__ col,
                            const float* __restrict__ es,
                            const float* __restrict__ ed,
                            const unsigned short* __restrict__ H,
                            const float* __restrict__ bias,
                            float* __restrict__ outX, int N) {
  const int lane = threadIdx.x & 63;
  const int n = blockIdx.x * (blockDim.x >> 6) + (threadIdx.x >> 6);
  if (n >= N) return;

  const int k0 = row_ptr[n];
  const int k1 = row_ptr[n + 1];
  const int deg = k1 - k0;
  const float edd = ed[n];
  const float self_lg = lrelu(es[n] + edd);

  float a0 = 0.f, a1 = 0.f;
  float den, sp;

  if (deg <= 64) {
    int k = k0 + lane;
    bool act = (k < k1);
    int c = act ? (int)col[k] : 0;
    float lg = act ? lrelu(es[c] + edd) : -3.0e38f;
    float m = fmaxf(wave_max(lg), self_lg);
    float p = act ? __expf(lg - m) : 0.f;
    sp = __expf(self_lg - m);
    den = wave_sum(p) + sp;
    int j = 0;
    for (; j + 8 <= deg; j += 8) {
      int ss[8];
      float pp[8];
      unsigned short uu[8];
#pragma unroll
      for (int q = 0; q < 8; ++q) {
        ss[q] = __shfl(c, j + q);
        pp[q] = __shfl(p, j + q);
      }
#pragma unroll
      for (int q = 0; q < 8; ++q) uu[q] = H[(size_t)ss[q] * 64 + lane];
#pragma unroll
      for (int q = 0; q < 8; ++q) {
        if (q & 1) a1 += pp[q] * bf1(uu[q]);
        else       a0 += pp[q] * bf1(uu[q]);
      }
    }
    for (; j < deg; ++j) {
      int s = __shfl(c, j);
      float pj = __shfl(p, j);
      a0 += pj * bf1(H[(size_t)s * 64 + lane]);
    }
  } else {
    float mloc = self_lg;
    for (int base = k0; base < k1; base += 64) {
      int k = base + lane;
      if (k < k1) mloc = fmaxf(mloc, lrelu(es[(int)col[k]] + edd));
    }
    float m = wave_max(mloc);
    sp = __expf(self_lg - m);
    den = sp;
    for (int base = k0; base < k1; base += 64) {
      int k = base + lane;
      bool act = (k < k1);
      int c = act ? (int)col[k] : 0;
      float p = act ? __expf(lrelu(es[c] + edd) - m) : 0.f;
      den += wave_sum(p);
      int len = min(64, k1 - base);
      for (int j = 0; j < len; ++j) {
        int s = __shfl(c, j);
        float pj = __shfl(p, j);
        a0 += pj * bf1(H[(size_t)s * 64 + lane]);
      }
    }
  }

  a0 += sp * bf1(H[(size_t)n * 64 + lane]);
  float v = (a0 + a1) / den + bias[lane];
  if (RELU) v = fmaxf(v, 0.f);
  outX[(size_t)n * 64 + lane] = v;
}

// ---------------------------------------------------------------------------

extern "C" void kernel_launch(void* const* d_in, const int* in_sizes, int n_in,
                              void* d_out, int out_size, void* d_ws, size_t ws_size,
                              hipStream_t stream) {
  const int C_HID = in_sizes[3];            // 128
  const int C_FIN = in_sizes[11];           // 64
  const int C_IN  = in_sizes[2] / C_HID;    // 128
  const int N     = in_sizes[0] / C_IN;     // 50000
  const int E     = in_sizes[1] / 2;        // 1.6M
  const int NPAD  = ((N + 63) / 64) * 64;

  const float* x = (const float*)d_in[0];
  const int* ei  = (const int*)d_in[1];
  const int* src = ei;
  const int* dst = ei + E;

  const float* W0  = (const float*)d_in[2];
  const float* as0 = (const float*)d_in[3];
  const float* ad0 = (const float*)d_in[4];
  const float* b0  = (const float*)d_in[5];
  const float* W1  = (const float*)d_in[6];
  const float* as1 = (const float*)d_in[7];
  const float* ad1 = (const float*)d_in[8];
  const float* b1  = (const float*)d_in[9];
  const float* W2  = (const float*)d_in[10];
  const float* as2 = (const float*)d_in[11];
  const float* ad2 = (const float*)d_in[12];
  const float* b2  = (const float*)d_in[13];

  // Workspace layout (256B aligned)
  char* base = (char*)d_ws;
  size_t off = 0;
  auto alloc = [&](size_t bytes) -> char* {
    char* p = base + off;
    off = (off + bytes + 255) & ~((size_t)255);
    return p;
  };
  const int NCH = (N + 255) / 256;
  unsigned short* XBF = (unsigned short*)alloc((size_t)NPAD * C_HID * 2);
  unsigned short* XB  = (unsigned short*)alloc((size_t)NPAD * C_HID * 2);
  unsigned short* H   = (unsigned short*)alloc((size_t)N * C_HID * 2);
  unsigned short* WT  = (unsigned short*)alloc((size_t)C_HID * 128 * 2);
  float* ES    = (float*)alloc((size_t)N * sizeof(float));
  float* ED    = (float*)alloc((size_t)N * sizeof(float));
  int*   RP    = (int*)alloc((size_t)(N + 1) * sizeof(int));
  int*   WP    = (int*)alloc((size_t)N * sizeof(int));
  void*  COL   = (void*)alloc((size_t)E * sizeof(int));   // u16 uses half
  int*   DEG   = (int*)alloc((size_t)N * sizeof(int));
  int*   CSUM  = (int*)alloc((size_t)NCH * sizeof(int));
  (void)ws_size;

  const int ET256 = (E + 255) / 256;
  const int wgrid = (N + 3) / 4;
  const int mgrid = NPAD / 64;
  const bool u16 = (N <= 65535);

  // ---- input conversion + CSR build ----
  conv_x_bf16<<<(NPAD * C_HID + 255) / 256, 256, 0, stream>>>(x, XBF, N * C_HID,
                                                              NPAD * C_HID);
  hipMemsetAsync(DEG, 0, (size_t)N * sizeof(int), stream);
  csr_count<<<ET256, 256, 0, stream>>>(dst, DEG, E);
  scan_partial<<<NCH, 256, 0, stream>>>(DEG, CSUM, N);
  scan_chunks<<<1, 256, 0, stream>>>(CSUM, NCH);
  scan_final<<<NCH, 256, 0, stream>>>(DEG, CSUM, RP, WP, N, E);
  {
    const int NPASS = 8;
    const int range = (N + NPASS - 1) / NPASS;
    if (u16)
      csr_scatter_ranged<unsigned short><<<2048, 256, 0, stream>>>(
          src, dst, WP, (unsigned short*)COL, E, range, NPASS);
    else
      csr_scatter_ranged<int><<<2048, 256, 0, stream>>>(
          src, dst, WP, (int*)COL, E, range, NPASS);
  }

  auto run_layers = [&](auto* col) {
    using IT = typename std::remove_pointer<decltype(col)>::type;
    // ---- Layer 0 ----
    conv_wt<<<(C_HID * 128 + 255) / 256, 256, 0, stream>>>(W0, WT, C_HID);
    gemm_mfma<128><<<mgrid, 256, 0, stream>>>(XBF, WT, as0, ad0, H, ES, ED, N);
    gat_fused128<true, true, IT><<<wgrid, 256, 0, stream>>>(RP, col, ES, ED, H, b0, XB, N);
    // ---- Layer 1 ----
    conv_wt<<<(C_HID * 128 + 255) / 256, 256, 0, stream>>>(W1, WT, C_HID);
    gemm_mfma<128><<<mgrid, 256, 0, stream>>>(XB, WT, as1, ad1, H, ES, ED, N);
    gat_fused128<true, true, IT><<<wgrid, 256, 0, stream>>>(RP, col, ES, ED, H, b1, XB, N);
    // ---- Layer 2 ----
    conv_wt<<<(C_FIN * 128 + 255) / 256, 256, 0, stream>>>(W2, WT, C_FIN);
    gemm_mfma<64><<<mgrid, 256, 0, stream>>>(XB, WT, as2, ad2, H, ES, ED, N);
    gat_fused64<false, IT><<<wgrid, 256, 0, stream>>>(RP, col, ES, ED, H, b2,
                                                      (float*)d_out, N);
  };

  if (u16) run_layers((unsigned short*)COL);
  else     run_layers((int*)COL);
  (void)out_size; (void)n_in;
}

// Round 13
// 410.806 us; speedup vs baseline: 4.5430x; 1.1188x over previous
//
#include <hip/hip_runtime.h>
#include <hip/hip_bf16.h>
#include <type_traits>

#define DEVFN __device__ __forceinline__

typedef __attribute__((ext_vector_type(8))) short bfrag;   // 8 bf16 (4 VGPRs)
typedef __attribute__((ext_vector_type(4))) float facc4;   // 4 fp32 acc

DEVFN float lrelu(float v) { return (v >= 0.f) ? v : 0.2f * v; }

// packed bf16x2 (uint) -> 2 floats; elem0 = low 16 bits
DEVFN float2 bf2x2(unsigned u) {
  return make_float2(__uint_as_float(u << 16), __uint_as_float(u & 0xFFFF0000u));
}
DEVFN float bf1(unsigned short b) { return __uint_as_float(((unsigned)b) << 16); }
DEVFN unsigned short f2bf(float f) {
  __hip_bfloat16 h = __float2bfloat16(f);
  return *reinterpret_cast<unsigned short*>(&h);
}
DEVFN unsigned packbf2(float x, float y) {
  return (unsigned)f2bf(x) | ((unsigned)f2bf(y) << 16);
}

DEVFN float wave_sum(float v) {
#pragma unroll
  for (int o = 1; o < 64; o <<= 1) v += __shfl_xor(v, o, 64);
  return v;
}
DEVFN float wave_max(float v) {
#pragma unroll
  for (int o = 1; o < 64; o <<= 1) v = fmaxf(v, __shfl_xor(v, o, 64));
  return v;
}

// ---------------------------------------------------------------------------
// MFMA GEMM + fused escore + fused weight conversion.
// H[N][C] = X[N][128] @ W[128][C] (fp32 W staged to bf16-transposed LDS).
// A_FP32: read X as fp32 and convert in-register (layer 0, avoids conv pass).
// mfma_f32_16x16x32_bf16 layouts (m89): A[m=lane&15][k=quad*8+j],
// B[k][n=lane&15], D[row=quad*4+reg][col=lane&15].
// ---------------------------------------------------------------------------
template<int C, bool A_FP32>
__global__ __launch_bounds__(256) void gemm_mfma(const void* __restrict__ Xin,
                                                 const float* __restrict__ W,
                                                 const float* __restrict__ a_src,
                                                 const float* __restrict__ a_dst,
                                                 unsigned short* __restrict__ H,
                                                 float* __restrict__ es,
                                                 float* __restrict__ ed,
                                                 int N) {
  constexpr int K = 128;
  constexpr int LSTR = K + 8;
  constexpr int NT = C / 16;
  __shared__ unsigned short WsT[C * LSTR];

  const int t = threadIdx.x;
  // stage W (fp32 row-major [k][C]) -> WsT[c][k] bf16, transposed
  for (int i = t; i < K * C; i += 256) {
    int k = i / C;               // C is a power of two -> shift
    int c = i - k * C;
    WsT[c * LSTR + k] = f2bf(W[i]);
  }
  __syncthreads();

  const int wave = t >> 6;
  const int lane = t & 63;
  const int l15 = lane & 15;
  const int quad = lane >> 4;
  const int arow = blockIdx.x * 64 + wave * 16 + l15;
  const bool avalid = arow < N;

  facc4 acc[NT];
#pragma unroll
  for (int i = 0; i < NT; ++i) acc[i] = (facc4){0.f, 0.f, 0.f, 0.f};

#pragma unroll
  for (int ks = 0; ks < 4; ++ks) {
    bfrag a;
    if (A_FP32) {
      if (avalid) {
        const float* xp = (const float*)Xin + (size_t)arow * K + quad * 8 + ks * 32;
        float4 u = *(const float4*)xp;
        float4 v = *(const float4*)(xp + 4);
        a[0] = (short)f2bf(u.x); a[1] = (short)f2bf(u.y);
        a[2] = (short)f2bf(u.z); a[3] = (short)f2bf(u.w);
        a[4] = (short)f2bf(v.x); a[5] = (short)f2bf(v.y);
        a[6] = (short)f2bf(v.z); a[7] = (short)f2bf(v.w);
      } else {
        a = (bfrag){0, 0, 0, 0, 0, 0, 0, 0};
      }
    } else {
      // XB is NPAD-padded; padding rows produce garbage, guarded at writes
      const unsigned short* xp =
          (const unsigned short*)Xin + (size_t)arow * K + quad * 8 + ks * 32;
      a = *(const bfrag*)xp;
    }
#pragma unroll
    for (int ct = 0; ct < NT; ++ct) {
      bfrag b = *(const bfrag*)(&WsT[(ct * 16 + l15) * LSTR + ks * 32 + quad * 8]);
      acc[ct] = __builtin_amdgcn_mfma_f32_16x16x32_bf16(a, b, acc[ct], 0, 0, 0);
    }
  }

  float asv[NT], adv[NT];
#pragma unroll
  for (int ct = 0; ct < NT; ++ct) {
    asv[ct] = a_src[ct * 16 + l15];
    adv[ct] = a_dst[ct * 16 + l15];
  }

  const int orow0 = blockIdx.x * 64 + wave * 16 + quad * 4;
#pragma unroll
  for (int r = 0; r < 4; ++r) {
    const int orow = orow0 + r;
    float ps = 0.f, pd = 0.f;
#pragma unroll
    for (int ct = 0; ct < NT; ++ct) {
      if (orow < N) H[(size_t)orow * C + ct * 16 + l15] = f2bf(acc[ct][r]);
      ps += acc[ct][r] * asv[ct];
      pd += acc[ct][r] * adv[ct];
    }
#pragma unroll
    for (int msk = 1; msk < 16; msk <<= 1) {
      ps += __shfl_xor(ps, msk, 64);
      pd += __shfl_xor(pd, msk, 64);
    }
    if (l15 == 0 && orow < N) { es[orow] = ps; ed[orow] = pd; }
  }
}

// ---------------------------------------------------------------------------
// CSR build, u16 path: radix partition (bucket = dst>>9, <=128 buckets).
// Phase 1: per-block histogram (+fused DEG count).
// Phase 2: exact offsets via exclusive scan of the bucket-major matrix.
// Phase 3: place edges grouped by bucket (sequential full-line writes).
// Phase 4: one WG per bucket -> COL region owned by one XCD (no write amp).
// ---------------------------------------------------------------------------
__global__ void hist_deg(const int* __restrict__ dst, int* __restrict__ deg,
                         int* __restrict__ hmat, int E, int nbk, int chunk) {
  __shared__ int hist[128];
  const int t = threadIdx.x;
  if (t < nbk) hist[t] = 0;
  __syncthreads();
  const int e0 = blockIdx.x * chunk;
  const int e1 = min(E, e0 + chunk);
  for (int e = e0 + t; e < e1; e += 256) {
    int d = dst[e];
    atomicAdd(deg + d, 1);
    atomicAdd(&hist[d >> 9], 1);
  }
  __syncthreads();
  if (t < nbk) hmat[t * gridDim.x + blockIdx.x] = hist[t];
}

__global__ void scan_partial(const int* __restrict__ in, int* __restrict__ csum, int n) {
  __shared__ int sh[256];
  int i = blockIdx.x * 256 + threadIdx.x;
  sh[threadIdx.x] = (i < n) ? in[i] : 0;
  __syncthreads();
  for (int o = 128; o > 0; o >>= 1) {
    if (threadIdx.x < o) sh[threadIdx.x] += sh[threadIdx.x + o];
    __syncthreads();
  }
  if (threadIdx.x == 0) csum[blockIdx.x] = sh[0];
}

__global__ void scan_chunks(int* __restrict__ csum, int nch) {
  __shared__ int sh[256];
  __shared__ int carry;
  if (threadIdx.x == 0) carry = 0;
  __syncthreads();
  for (int base = 0; base < nch; base += 256) {
    int i = base + threadIdx.x;
    int v = (i < nch) ? csum[i] : 0;
    sh[threadIdx.x] = v;
    __syncthreads();
    for (int o = 1; o < 256; o <<= 1) {
      int t = (threadIdx.x >= o) ? sh[threadIdx.x - o] : 0;
      __syncthreads();
      sh[threadIdx.x] += t;
      __syncthreads();
    }
    if (i < nch) csum[i] = carry + sh[threadIdx.x] - v;
    __syncthreads();
    if (threadIdx.x == 255) carry += sh[255];
    __syncthreads();
  }
}

// exclusive scan of DEG -> rp (+wp for fallback); rp[N]=E
__global__ void scan_final(const int* __restrict__ deg, const int* __restrict__ csum,
                           int* __restrict__ rp, int* __restrict__ wp, int N, int E) {
  __shared__ int sh[256];
  int i = blockIdx.x * 256 + threadIdx.x;
  int v = (i < N) ? deg[i] : 0;
  sh[threadIdx.x] = v;
  __syncthreads();
  for (int o = 1; o < 256; o <<= 1) {
    int t = (threadIdx.x >= o) ? sh[threadIdx.x - o] : 0;
    __syncthreads();
    sh[threadIdx.x] += t;
    __syncthreads();
  }
  if (i < N) {
    int r = csum[blockIdx.x] + sh[threadIdx.x] - v;
    rp[i] = r;
    wp[i] = r;
  }
  if (blockIdx.x == 0 && threadIdx.x == 0) rp[N] = E;
}

// generic exclusive scan -> out
__global__ void scan_final_excl(const int* __restrict__ in, const int* __restrict__ csum,
                                int* __restrict__ out, int n) {
  __shared__ int sh[256];
  int i = blockIdx.x * 256 + threadIdx.x;
  int v = (i < n) ? in[i] : 0;
  sh[threadIdx.x] = v;
  __syncthreads();
  for (int o = 1; o < 256; o <<= 1) {
    int t = (threadIdx.x >= o) ? sh[threadIdx.x - o] : 0;
    __syncthreads();
    sh[threadIdx.x] += t;
    __syncthreads();
  }
  if (i < n) out[i] = csum[blockIdx.x] + sh[threadIdx.x] - v;
}

__global__ void place_pass(const int* __restrict__ src, const int* __restrict__ dst,
                           const int* __restrict__ off, int2* __restrict__ be,
                           int E, int nbk, int chunk) {
  __shared__ int cur[128];
  const int t = threadIdx.x;
  if (t < nbk) cur[t] = off[t * gridDim.x + blockIdx.x];
  __syncthreads();
  const int e0 = blockIdx.x * chunk;
  const int e1 = min(E, e0 + chunk);
  for (int e = e0 + t; e < e1; e += 256) {
    int d = dst[e];
    int s = src[e];
    int p = atomicAdd(&cur[d >> 9], 1);
    be[p] = make_int2(s, d);
  }
}

__global__ void bucket_final(const int2* __restrict__ be, const int* __restrict__ off,
                             const int* __restrict__ rp, unsigned short* __restrict__ col,
                             int E, int N, int nbk, int pblk) {
  __shared__ int cur[512];
  const int b = blockIdx.x;
  const int n0 = b << 9;
  const int cnt = min(512, N - n0);
  const int t = threadIdx.x;
  for (int i = t; i < cnt; i += 256) cur[i] = rp[n0 + i];
  __syncthreads();
  const int e0 = off[b * pblk];
  const int e1 = (b + 1 < nbk) ? off[(b + 1) * pblk] : E;
  for (int e = e0 + t; e < e1; e += 256) {
    int2 sd = be[e];
    int p = atomicAdd(&cur[sd.y - n0], 1);
    col[p] = (unsigned short)sd.x;
  }
}

// Fallback (N > 65535): ranged multi-pass scatter with int COL.
__global__ void csr_scatter_ranged(const int* __restrict__ src,
                                   const int* __restrict__ dst,
                                   int* __restrict__ wp, int* __restrict__ col,
                                   int E, int range, int npass) {
  const int stride = gridDim.x * blockDim.x;
  const int gid = blockIdx.x * blockDim.x + threadIdx.x;
  for (int pass = 0; pass < npass; ++pass) {
    const int lo = pass * range;
    const int hi = lo + range;
    for (int e = gid; e < E; e += stride) {
      int d = dst[e];
      if (d >= lo && d < hi) {
        int p = atomicAdd(wp + d, 1);
        col[p] = src[e];
      }
    }
  }
}

__global__ void csr_count(const int* __restrict__ dst, int* __restrict__ deg, int E) {
  int e = blockIdx.x * blockDim.x + threadIdx.x;
  if (e < E) atomicAdd(deg + dst[e], 1);
}

// ---------------------------------------------------------------------------
// Fully fused GAT edge stage (softmax in registers + gather via __shfl
// broadcast). 8-edge batches -> 8 independent H loads in flight per wave.
// ---------------------------------------------------------------------------
template<bool RELU, bool OUT_BF16, typename IT>
__global__ void gat_fused128(const int* __restrict__ row_ptr,
                             const IT* __restrict__ col,
                             const float* __restrict__ es,
                             const float* __restrict__ ed,
                             const unsigned short* __restrict__ H,
                             const float* __restrict__ bias,
                             void* __restrict__ outX, int N) {
  const int lane = threadIdx.x & 63;
  const int n = blockIdx.x * (blockDim.x >> 6) + (threadIdx.x >> 6);
  if (n >= N) return;

  const int k0 = row_ptr[n];
  const int k1 = row_ptr[n + 1];
  const int deg = k1 - k0;
  const float edd = ed[n];
  const float self_lg = lrelu(es[n] + edd);

  const unsigned* Hp = (const unsigned*)H;   // bf16x2 per lane
  float ax0 = 0.f, ay0 = 0.f, ax1 = 0.f, ay1 = 0.f;
  float den, sp;

  if (deg <= 64) {
    int k = k0 + lane;
    bool act = (k < k1);
    int c = act ? (int)col[k] : 0;
    float lg = act ? lrelu(es[c] + edd) : -3.0e38f;
    float m = fmaxf(wave_max(lg), self_lg);
    float p = act ? __expf(lg - m) : 0.f;
    sp = __expf(self_lg - m);
    den = wave_sum(p) + sp;
    int j = 0;
    for (; j + 8 <= deg; j += 8) {
      int ss[8];
      float pp[8];
      unsigned uu[8];
#pragma unroll
      for (int q = 0; q < 8; ++q) {
        ss[q] = __shfl(c, j + q);
        pp[q] = __shfl(p, j + q);
      }
#pragma unroll
      for (int q = 0; q < 8; ++q) uu[q] = Hp[(size_t)ss[q] * 64 + lane];
#pragma unroll
      for (int q = 0; q < 8; ++q) {
        float2 h = bf2x2(uu[q]);
        if (q & 1) { ax1 += pp[q] * h.x; ay1 += pp[q] * h.y; }
        else       { ax0 += pp[q] * h.x; ay0 += pp[q] * h.y; }
      }
    }
    for (; j < deg; ++j) {
      int s = __shfl(c, j);
      float pj = __shfl(p, j);
      float2 h = bf2x2(Hp[(size_t)s * 64 + lane]);
      ax0 += pj * h.x; ay0 += pj * h.y;
    }
  } else {
    float mloc = self_lg;
    for (int base = k0; base < k1; base += 64) {
      int k = base + lane;
      if (k < k1) mloc = fmaxf(mloc, lrelu(es[(int)col[k]] + edd));
    }
    float m = wave_max(mloc);
    sp = __expf(self_lg - m);
    den = sp;
    for (int base = k0; base < k1; base += 64) {
      int k = base + lane;
      bool act = (k < k1);
      int c = act ? (int)col[k] : 0;
      float p = act ? __expf(lrelu(es[c] + edd) - m) : 0.f;
      den += wave_sum(p);
      int len = min(64, k1 - base);
      for (int j = 0; j < len; ++j) {
        int s = __shfl(c, j);
        float pj = __shfl(p, j);
        float2 h = bf2x2(Hp[(size_t)s * 64 + lane]);
        ax0 += pj * h.x; ay0 += pj * h.y;
      }
    }
  }

  float2 hv = bf2x2(Hp[(size_t)n * 64 + lane]);
  ax0 += sp * hv.x; ay0 += sp * hv.y;
  float inv = 1.f / den;
  float2 bv = ((const float2*)bias)[lane];
  float vx = (ax0 + ax1) * inv + bv.x;
  float vy = (ay0 + ay1) * inv + bv.y;
  if (RELU) { vx = fmaxf(vx, 0.f); vy = fmaxf(vy, 0.f); }
  if (OUT_BF16)
    ((unsigned*)outX)[(size_t)n * 64 + lane] = packbf2(vx, vy);
  else
    ((float2*)outX)[(size_t)n * 64 + lane] = make_float2(vx, vy);
}

template<bool RELU, typename IT>
__global__ void gat_fused64(const int* __restrict__ row_ptr,
                            const IT* __restrict__ col,
                            const float* __restrict__ es,
                            const float* __restrict__ ed,
                            const unsigned short* __restrict__ H,
                            const float* __restrict__ bias,
                            float* __restrict__ outX, int N) {
  const int lane = threadIdx.x & 63;
  const int n = blockIdx.x * (blockDim.x >> 6) + (threadIdx.x >> 6);
  if (n >= N) return;

  const int k0 = row_ptr[n];
  const int k1 = row_ptr[n + 1];
  const int deg = k1 - k0;
  const float edd = ed[n];
  const float self_lg = lrelu(es[n] + edd);

  float a0 = 0.f, a1 = 0.f;
  float den, sp;

  if (deg <= 64) {
    int k = k0 + lane;
    bool act = (k < k1);
    int c = act ? (int)col[k] : 0;
    float lg = act ? lrelu(es[c] + edd) : -3.0e38f;
    float m = fmaxf(wave_max(lg), self_lg);
    float p = act ? __expf(lg - m) : 0.f;
    sp = __expf(self_lg - m);
    den = wave_sum(p) + sp;
    int j = 0;
    for (; j + 8 <= deg; j += 8) {
      int ss[8];
      float pp[8];
      unsigned short uu[8];
#pragma unroll
      for (int q = 0; q < 8; ++q) {
        ss[q] = __shfl(c, j + q);
        pp[q] = __shfl(p, j + q);
      }
#pragma unroll
      for (int q = 0; q < 8; ++q) uu[q] = H[(size_t)ss[q] * 64 + lane];
#pragma unroll
      for (int q = 0; q < 8; ++q) {
        if (q & 1) a1 += pp[q] * bf1(uu[q]);
        else       a0 += pp[q] * bf1(uu[q]);
      }
    }
    for (; j < deg; ++j) {
      int s = __shfl(c, j);
      float pj = __shfl(p, j);
      a0 += pj * bf1(H[(size_t)s * 64 + lane]);
    }
  } else {
    float mloc = self_lg;
    for (int base = k0; base < k1; base += 64) {
      int k = base + lane;
      if (k < k1) mloc = fmaxf(mloc, lrelu(es[(int)col[k]] + edd));
    }
    float m = wave_max(mloc);
    sp = __expf(self_lg - m);
    den = sp;
    for (int base = k0; base < k1; base += 64) {
      int k = base + lane;
      bool act = (k < k1);
      int c = act ? (int)col[k] : 0;
      float p = act ? __expf(lrelu(es[c] + edd) - m) : 0.f;
      den += wave_sum(p);
      int len = min(64, k1 - base);
      for (int j = 0; j < len; ++j) {
        int s = __shfl(c, j);
        float pj = __shfl(p, j);
        a0 += pj * bf1(H[(size_t)s * 64 + lane]);
      }
    }
  }

  a0 += sp * bf1(H[(size_t)n * 64 + lane]);
  float v = (a0 + a1) / den + bias[lane];
  if (RELU) v = fmaxf(v, 0.f);
  outX[(size_t)n * 64 + lane] = v;
}

// ---------------------------------------------------------------------------

extern "C" void kernel_launch(void* const* d_in, const int* in_sizes, int n_in,
                              void* d_out, int out_size, void* d_ws, size_t ws_size,
                              hipStream_t stream) {
  const int C_HID = in_sizes[3];            // 128
  const int C_FIN = in_sizes[11];           // 64
  const int C_IN  = in_sizes[2] / C_HID;    // 128
  const int N     = in_sizes[0] / C_IN;     // 50000
  const int E     = in_sizes[1] / 2;        // 1.6M
  const int NPAD  = ((N + 63) / 64) * 64;

  const float* x = (const float*)d_in[0];
  const int* ei  = (const int*)d_in[1];
  const int* src = ei;
  const int* dst = ei + E;

  const float* W0  = (const float*)d_in[2];
  const float* as0 = (const float*)d_in[3];
  const float* ad0 = (const float*)d_in[4];
  const float* b0  = (const float*)d_in[5];
  const float* W1  = (const float*)d_in[6];
  const float* as1 = (const float*)d_in[7];
  const float* ad1 = (const float*)d_in[8];
  const float* b1  = (const float*)d_in[9];
  const float* W2  = (const float*)d_in[10];
  const float* as2 = (const float*)d_in[11];
  const float* ad2 = (const float*)d_in[12];
  const float* b2  = (const float*)d_in[13];

  // Workspace layout (256B aligned)
  char* base = (char*)d_ws;
  size_t off = 0;
  auto alloc = [&](size_t bytes) -> char* {
    char* p = base + off;
    off = (off + bytes + 255) & ~((size_t)255);
    return p;
  };
  const int PBLK = 512;                     // partition blocks
  const int NBK  = (N + 511) >> 9;          // buckets of 512 dst nodes (<=128)
  const int M    = NBK * PBLK;              // offset-matrix size
  const int NCH  = (N + 255) / 256;
  const int MCH  = (M + 255) / 256;
  const int SCH  = (NCH > MCH ? NCH : MCH);

  unsigned short* XB  = (unsigned short*)alloc((size_t)NPAD * C_HID * 2);
  unsigned short* H   = (unsigned short*)alloc((size_t)N * C_HID * 2);
  float* ES    = (float*)alloc((size_t)N * sizeof(float));
  float* ED    = (float*)alloc((size_t)N * sizeof(float));
  int*   RP    = (int*)alloc((size_t)(N + 1) * sizeof(int));
  int*   WP    = (int*)alloc((size_t)N * sizeof(int));
  void*  COL   = (void*)alloc((size_t)E * sizeof(int));   // u16 uses half
  int*   DEG   = (int*)alloc((size_t)N * sizeof(int));
  int*   CSUM  = (int*)alloc((size_t)SCH * sizeof(int));
  int*   HMAT  = (int*)alloc((size_t)M * sizeof(int));
  int*   OFF   = (int*)alloc((size_t)M * sizeof(int));
  int2*  BE    = (int2*)alloc((size_t)E * sizeof(int2));
  (void)ws_size;

  const int wgrid = (N + 3) / 4;
  const int mgrid = NPAD / 64;
  const bool u16 = (N <= 65535);

  // ---- CSR build ----
  hipMemsetAsync(DEG, 0, (size_t)N * sizeof(int), stream);
  if (u16) {
    const int CHUNK = (E + PBLK - 1) / PBLK;
    hist_deg<<<PBLK, 256, 0, stream>>>(dst, DEG, HMAT, E, NBK, CHUNK);
    scan_partial<<<NCH, 256, 0, stream>>>(DEG, CSUM, N);
    scan_chunks<<<1, 256, 0, stream>>>(CSUM, NCH);
    scan_final<<<NCH, 256, 0, stream>>>(DEG, CSUM, RP, WP, N, E);
    scan_partial<<<MCH, 256, 0, stream>>>(HMAT, CSUM, M);
    scan_chunks<<<1, 256, 0, stream>>>(CSUM, MCH);
    scan_final_excl<<<MCH, 256, 0, stream>>>(HMAT, CSUM, OFF, M);
    place_pass<<<PBLK, 256, 0, stream>>>(src, dst, OFF, BE, E, NBK, CHUNK);
    bucket_final<<<NBK, 256, 0, stream>>>(BE, OFF, RP, (unsigned short*)COL,
                                          E, N, NBK, PBLK);
  } else {
    const int ET256 = (E + 255) / 256;
    csr_count<<<ET256, 256, 0, stream>>>(dst, DEG, E);
    scan_partial<<<NCH, 256, 0, stream>>>(DEG, CSUM, N);
    scan_chunks<<<1, 256, 0, stream>>>(CSUM, NCH);
    scan_final<<<NCH, 256, 0, stream>>>(DEG, CSUM, RP, WP, N, E);
    const int NPASS = 8;
    const int range = (N + NPASS - 1) / NPASS;
    csr_scatter_ranged<<<2048, 256, 0, stream>>>(src, dst, WP, (int*)COL, E,
                                                 range, NPASS);
  }

  auto run_layers = [&](auto* col) {
    using IT = typename std::remove_pointer<decltype(col)>::type;
    // ---- Layer 0: x(fp32) -> H(+es/ed) -> XB (relu, bf16) ----
    gemm_mfma<128, true><<<mgrid, 256, 0, stream>>>(x, W0, as0, ad0, H, ES, ED, N);
    gat_fused128<true, true, IT><<<wgrid, 256, 0, stream>>>(RP, col, ES, ED, H, b0, XB, N);
    // ---- Layer 1: XB -> H(+es/ed) -> XB (relu, bf16) ----
    gemm_mfma<128, false><<<mgrid, 256, 0, stream>>>(XB, W1, as1, ad1, H, ES, ED, N);
    gat_fused128<true, true, IT><<<wgrid, 256, 0, stream>>>(RP, col, ES, ED, H, b1, XB, N);
    // ---- Layer 2: XB -> H(+es/ed) -> d_out (no relu, fp32) ----
    gemm_mfma<64, false><<<mgrid, 256, 0, stream>>>(XB, W2, as2, ad2, H, ES, ED, N);
    gat_fused64<false, IT><<<wgrid, 256, 0, stream>>>(RP, col, ES, ED, H, b2,
                                                      (float*)d_out, N);
  };

  if (u16) run_layers((unsigned short*)COL);
  else     run_layers((int*)COL);
  (void)out_size; (void)n_in;
}